// Round 1
// baseline (787.882 us; speedup 1.0000x reference)
//
#include <hip/hip_runtime.h>
#include <hip/hip_bf16.h>
#include <stdint.h>

typedef unsigned short u16;
typedef __attribute__((ext_vector_type(8))) short short8;
typedef __attribute__((ext_vector_type(4))) float floatx4;

#define BT 200      // B*T
#define NOBJ 30
#define KPAD 4128   // 4097 padded to mult of 32
#define DIN 4097
#define DH1 512
#define DH2 256
#define DFF 512
#define LDSTR 40    // LDS row stride (32 + 8 pad)

__device__ __forceinline__ u16 f2bf(float f) {
    union { float f; uint32_t u; } c; c.f = f;
    uint32_t u = c.u;
    u += 0x7FFF + ((u >> 16) & 1);
    return (u16)(u >> 16);
}
__device__ __forceinline__ float bf2f(u16 h) {
    union { uint32_t u; float f; } c; c.u = ((uint32_t)h) << 16;
    return c.f;
}

// ---------------- weight folding ----------------
// Wc1T[j][k] = W1a[k][j] - W2a[k][j]/29 ; W2aTs[j][k] = W2a[k][j]/29  (bf16, K padded)
__global__ void fold_big(const float* __restrict__ W1a, const float* __restrict__ W2a,
                         u16* __restrict__ Wc1T, u16* __restrict__ W2aTs) {
    __shared__ float t1[32][33];
    __shared__ float t2[32][33];
    int kb = blockIdx.x * 32, jb = blockIdx.y * 32;
    int tx = threadIdx.x & 31, ty = threadIdx.x >> 5;   // 32 x 8
    #pragma unroll
    for (int r = 0; r < 32; r += 8) {
        int k = kb + ty + r, j = jb + tx;
        float a = 0.f, b = 0.f;
        if (k < DIN) { a = W1a[k * DH1 + j]; b = W2a[k * DH1 + j]; }
        float bs = b * (1.f / 29.f);
        t1[ty + r][tx] = a - bs;
        t2[ty + r][tx] = bs;
    }
    __syncthreads();
    #pragma unroll
    for (int r = 0; r < 32; r += 8) {
        int j = jb + ty + r, k = kb + tx;
        Wc1T[(size_t)j * KPAD + k]  = f2bf(t1[tx][ty + r]);
        W2aTs[(size_t)j * KPAD + k] = f2bf(t2[tx][ty + r]);
    }
}

// Wc2T[j][k] = W1b[k][j] - W2b[k][j]/29 ; W2bTs[j][k] = W2b[k][j]/29   (256 x 512)
__global__ void fold_small(const float* __restrict__ W1b, const float* __restrict__ W2b,
                           u16* __restrict__ Wc2T, u16* __restrict__ W2bTs) {
    int idx = blockIdx.x * 256 + threadIdx.x;   // 256*512 total
    int j = idx >> 9, k = idx & 511;
    float a = W1b[k * DH2 + j];
    float b = W2b[k * DH2 + j] * (1.f / 29.f);
    Wc2T[j * DH1 + k]  = f2bf(a - b);
    W2bTs[j * DH1 + k] = f2bf(b);
}

// ---------------- X concat + bf16 convert + node-sum ----------------
// Xb: (6000, KPAD) bf16 = [features | depth | 0...]; Sb: (200, KPAD) bf16 node sums
__global__ void sum_convert(const float* __restrict__ feat, const float* __restrict__ depth,
                            u16* __restrict__ Xb, u16* __restrict__ Sb) {
    int bt = blockIdx.x;
    int k = blockIdx.y * 256 + threadIdx.x;
    if (k >= KPAD) return;
    float acc = 0.f;
    for (int n = 0; n < NOBJ; n++) {
        float v;
        if (k < 4096)       v = feat[(size_t)(bt * NOBJ + n) * 4096 + k];
        else if (k == 4096) v = depth[bt * NOBJ + n];
        else                v = 0.f;
        acc += v;
        Xb[(size_t)(bt * NOBJ + n) * KPAD + k] = f2bf(v);
    }
    Sb[(size_t)bt * KPAD + k] = f2bf(acc);
}

// ---------------- generic bf16 MFMA GEMM, B^T layout ----------------
// C[M,N] = A[M,K] @ B^T[N,K]; epilogue: + row_add[row/row_div][col] + col_add[col]; relu; store f32/bf16
__global__ __launch_bounds__(256) void gemm_bt(
    const u16* __restrict__ A, const u16* __restrict__ B,
    int M, int N, int K,
    const float* __restrict__ row_add, int row_div,
    const float* __restrict__ col_add, int relu,
    float* __restrict__ outF, u16* __restrict__ outB) {
    __shared__ __align__(16) u16 Al[128 * LDSTR];
    __shared__ __align__(16) u16 Bl[128 * LDSTR];
    int tid = threadIdx.x;
    int wave = tid >> 6, lane = tid & 63;
    int m0 = blockIdx.x * 128, n0 = blockIdx.y * 128;
    floatx4 acc[4][4] = {};
    int wm = (wave & 1) * 64, wn = (wave >> 1) * 64;
    int lrow = lane & 15, ks = (lane >> 4) * 8;

    for (int k0 = 0; k0 < K; k0 += 32) {
        #pragma unroll
        for (int it = 0; it < 2; it++) {
            int c = tid + it * 256;          // 512 chunks of 8 bf16
            int row = c >> 2, kc = (c & 3) << 3;
            int gr = m0 + row;
            short8 va = {};
            if (gr < M) va = *(const short8*)(A + (size_t)gr * K + k0 + kc);
            *(short8*)(Al + row * LDSTR + kc) = va;
            int gn = n0 + row;
            short8 vb = {};
            if (gn < N) vb = *(const short8*)(B + (size_t)gn * K + k0 + kc);
            *(short8*)(Bl + row * LDSTR + kc) = vb;
        }
        __syncthreads();
        short8 af[4], bfv[4];
        #pragma unroll
        for (int i = 0; i < 4; i++)
            af[i] = *(short8*)(Al + (wm + i * 16 + lrow) * LDSTR + ks);
        #pragma unroll
        for (int j = 0; j < 4; j++)
            bfv[j] = *(short8*)(Bl + (wn + j * 16 + lrow) * LDSTR + ks);
        #pragma unroll
        for (int i = 0; i < 4; i++)
            #pragma unroll
            for (int j = 0; j < 4; j++)
                acc[i][j] = __builtin_amdgcn_mfma_f32_16x16x32_bf16(af[i], bfv[j], acc[i][j], 0, 0, 0);
        __syncthreads();
    }

    int lcol = lane & 15, rquad = lane >> 4;
    #pragma unroll
    for (int i = 0; i < 4; i++) {
        #pragma unroll
        for (int j = 0; j < 4; j++) {
            #pragma unroll
            for (int r = 0; r < 4; r++) {
                int row = m0 + wm + i * 16 + rquad * 4 + r;
                int col = n0 + wn + j * 16 + lcol;
                if (row < M && col < N) {
                    float v = acc[i][j][r];
                    if (row_add) v += row_add[(row / row_div) * N + col];
                    if (col_add) v += col_add[col];
                    if (relu)    v = v > 0.f ? v : 0.f;
                    if (outF) outF[(size_t)row * N + col] = v;
                    if (outB) outB[(size_t)row * N + col] = f2bf(v);
                }
            }
        }
    }
}

// ---------------- node-sum of h (bf16 512) ----------------
__global__ void sum_h(const u16* __restrict__ hb, u16* __restrict__ Shb) {
    int bt = blockIdx.x;
    for (int k = threadIdx.x; k < DH1; k += 256) {
        float acc = 0.f;
        for (int n = 0; n < NOBJ; n++)
            acc += bf2f(hb[(size_t)(bt * NOBJ + n) * DH1 + k]);
        Shb[bt * DH1 + k] = f2bf(acc);
    }
}

// ---------------- mean-pool h2 -> g ----------------
__global__ void pool_g(const u16* __restrict__ h2b, float* __restrict__ g) {
    int bt = blockIdx.x, c = threadIdx.x;
    float acc = 0.f;
    for (int n = 0; n < NOBJ; n++)
        acc += bf2f(h2b[(size_t)(bt * NOBJ + n) * DH2 + c]);
    g[bt * DH2 + c] = acc * (1.f / 30.f);
}

// ---------------- QKV projections ----------------
__global__ void qkv_proj(const float* __restrict__ g,
                         const float* __restrict__ Wq, const float* __restrict__ Wk,
                         const float* __restrict__ Wv,
                         float* __restrict__ q, float* __restrict__ k, float* __restrict__ v) {
    __shared__ float gl[DH2];
    int bt = blockIdx.x, j = threadIdx.x;
    gl[j] = g[bt * DH2 + j];
    __syncthreads();
    float aq = 0.f, ak = 0.f, av = 0.f;
    for (int kk = 0; kk < DH2; kk++) {
        float x = gl[kk];
        aq += x * Wq[kk * DH2 + j];
        ak += x * Wk[kk * DH2 + j];
        av += x * Wv[kk * DH2 + j];
    }
    q[bt * DH2 + j] = aq;
    k[bt * DH2 + j] = ak;
    v[bt * DH2 + j] = av;
}

// ---------------- attention (per b,h,tq) ----------------
__global__ void attn_kernel(const float* __restrict__ q, const float* __restrict__ kk,
                            const float* __restrict__ vv, float* __restrict__ ctx) {
    int tq = blockIdx.x, h = blockIdx.y, b = blockIdx.z;
    int tid = threadIdx.x;
    __shared__ float qs[64];
    __shared__ float sc[100];
    __shared__ float inv;
    if (tid < 64) qs[tid] = q[(b * 100 + tq) * DH2 + h * 64 + tid];
    __syncthreads();
    if (tid < 100) {
        const float* kr = &kk[(b * 100 + tid) * DH2 + h * 64];
        float s = 0.f;
        for (int d = 0; d < 64; d++) s += qs[d] * kr[d];
        sc[tid] = s * 0.125f;
    }
    __syncthreads();
    if (tid == 0) {
        float mx = -1e30f;
        for (int i = 0; i < 100; i++) mx = fmaxf(mx, sc[i]);
        float sm = 0.f;
        for (int i = 0; i < 100; i++) { float p = __expf(sc[i] - mx); sc[i] = p; sm += p; }
        inv = 1.f / sm;
    }
    __syncthreads();
    if (tid < 64) {
        float o = 0.f;
        for (int s = 0; s < 100; s++) o += sc[s] * vv[(b * 100 + s) * DH2 + h * 64 + tid];
        ctx[(b * 100 + tq) * DH2 + h * 64 + tid] = o * inv;
    }
}

// ---------------- fused head: Wo-proj + LN1 + FFN + LN2 + classifier ----------------
__device__ __forceinline__ float block_sum256(float v, volatile float* red) {
    #pragma unroll
    for (int o = 32; o > 0; o >>= 1) v += __shfl_down(v, o);
    int w = threadIdx.x >> 6;
    __syncthreads();
    if ((threadIdx.x & 63) == 0) red[w] = v;
    __syncthreads();
    return red[0] + red[1] + red[2] + red[3];
}

__global__ void head_kernel(const float* __restrict__ ctx, const float* __restrict__ g,
                            const float* __restrict__ Wo,
                            const float* __restrict__ ln1g, const float* __restrict__ ln1b,
                            const float* __restrict__ Wf1, const float* __restrict__ bf1,
                            const float* __restrict__ Wf2, const float* __restrict__ bf2,
                            const float* __restrict__ ln2g, const float* __restrict__ ln2b,
                            const float* __restrict__ Wc, const float* __restrict__ bc,
                            float* __restrict__ out) {
    __shared__ float ctxl[DH2];
    __shared__ float yl[DH2];
    __shared__ float ffl[DFF];
    __shared__ float red[4];
    int row = blockIdx.x, tid = threadIdx.x;
    ctxl[tid] = ctx[row * DH2 + tid];
    __syncthreads();
    float o = 0.f;
    for (int k = 0; k < DH2; k++) o += ctxl[k] * Wo[k * DH2 + tid];
    float t = g[row * DH2 + tid] + o;
    float mu  = block_sum256(t, red) * (1.f / DH2);
    float ex2 = block_sum256(t * t, red) * (1.f / DH2);
    float y = (t - mu) * rsqrtf(ex2 - mu * mu + 1e-5f) * ln1g[tid] + ln1b[tid];
    yl[tid] = y;
    __syncthreads();
    for (int jj = tid; jj < DFF; jj += 256) {
        float a = bf1[jj];
        for (int k = 0; k < DH2; k++) a += yl[k] * Wf1[k * DFF + jj];
        ffl[jj] = a > 0.f ? a : 0.f;
    }
    __syncthreads();
    float o2 = bf2[tid];
    for (int k = 0; k < DFF; k++) o2 += ffl[k] * Wf2[k * DH2 + tid];
    float z0 = y + o2;
    float mu2  = block_sum256(z0, red) * (1.f / DH2);
    float ex22 = block_sum256(z0 * z0, red) * (1.f / DH2);
    float z = (z0 - mu2) * rsqrtf(ex22 - mu2 * mu2 + 1e-5f) * ln2g[tid] + ln2b[tid];
    float logit = block_sum256(z * Wc[tid], red) + bc[0];
    if (tid == 0) {
        out[row]       = 1.f / (1.f + __expf(-logit));
        out[BT + row]  = 0.f;   // uncertainty == 0 in eval mode
    }
}

// ---------------- launch ----------------
extern "C" void kernel_launch(void* const* d_in, const int* in_sizes, int n_in,
                              void* d_out, int out_size, void* d_ws, size_t ws_size,
                              hipStream_t stream) {
    const float* feat  = (const float*)d_in[0];
    const float* depth = (const float*)d_in[1];
    const float* W1a = (const float*)d_in[2];
    const float* W2a = (const float*)d_in[3];
    const float* b1a = (const float*)d_in[4];
    const float* W1b = (const float*)d_in[5];
    const float* W2b = (const float*)d_in[6];
    const float* b1b = (const float*)d_in[7];
    const float* Wq  = (const float*)d_in[8];
    const float* Wk  = (const float*)d_in[9];
    const float* Wv  = (const float*)d_in[10];
    const float* Wo  = (const float*)d_in[11];
    const float* ln1g = (const float*)d_in[12];
    const float* ln1b = (const float*)d_in[13];
    const float* Wf1 = (const float*)d_in[14];
    const float* bf1 = (const float*)d_in[15];
    const float* Wf2 = (const float*)d_in[16];
    const float* bf2 = (const float*)d_in[17];
    const float* ln2g = (const float*)d_in[18];
    const float* ln2b = (const float*)d_in[19];
    const float* Wc  = (const float*)d_in[20];
    const float* bc  = (const float*)d_in[21];
    float* out = (float*)d_out;
    char* ws = (char*)d_ws;

    size_t off = 0;
    u16* Xb    = (u16*)(ws + off); off += (size_t)6000 * KPAD * 2;   // 49,536,000
    u16* Sb    = (u16*)(ws + off); off += (size_t)BT * KPAD * 2;     //  1,651,200
    u16* Wc1T  = (u16*)(ws + off); off += (size_t)DH1 * KPAD * 2;    //  4,227,072
    u16* W2aTs = (u16*)(ws + off); off += (size_t)DH1 * KPAD * 2;
    u16* Wc2T  = (u16*)(ws + off); off += (size_t)DH2 * DH1 * 2;
    u16* W2bTs = (u16*)(ws + off); off += (size_t)DH2 * DH1 * 2;
    u16* hb    = (u16*)(ws + off); off += (size_t)6000 * DH1 * 2;
    u16* Shb   = (u16*)(ws + off); off += (size_t)BT * DH1 * 2;
    u16* h2b   = (u16*)(ws + off); off += (size_t)6000 * DH2 * 2;
    float* u   = (float*)(ws + off); off += (size_t)BT * DH1 * 4;
    float* u2  = (float*)(ws + off); off += (size_t)BT * DH2 * 4;
    float* g   = (float*)(ws + off); off += (size_t)BT * DH2 * 4;
    float* q   = (float*)(ws + off); off += (size_t)BT * DH2 * 4;
    float* k   = (float*)(ws + off); off += (size_t)BT * DH2 * 4;
    float* v   = (float*)(ws + off); off += (size_t)BT * DH2 * 4;
    float* ctx = (float*)(ws + off); off += (size_t)BT * DH2 * 4;

    // weight prep + input prep
    fold_big<<<dim3(KPAD / 32, DH1 / 32), 256, 0, stream>>>(W1a, W2a, Wc1T, W2aTs);
    fold_small<<<(DH2 * DH1) / 256, 256, 0, stream>>>(W1b, W2b, Wc2T, W2bTs);
    sum_convert<<<dim3(BT, (KPAD + 255) / 256), 256, 0, stream>>>(feat, depth, Xb, Sb);

    // u = (S/29) @ W2a + b1a          (200 x 512)
    gemm_bt<<<dim3(2, 4), 256, 0, stream>>>(Sb, W2aTs, BT, DH1, KPAD,
                                            nullptr, 1, b1a, 0, u, nullptr);
    // h = relu(X @ Wc1 + u[bt])       (6000 x 512)
    gemm_bt<<<dim3(47, 4), 256, 0, stream>>>(Xb, Wc1T, 6000, DH1, KPAD,
                                             u, NOBJ, nullptr, 1, nullptr, hb);
    // S_h
    sum_h<<<BT, 256, 0, stream>>>(hb, Shb);
    // u2 = (S_h/29) @ W2b + b1b       (200 x 256)
    gemm_bt<<<dim3(2, 2), 256, 0, stream>>>(Shb, W2bTs, BT, DH2, DH1,
                                            nullptr, 1, b1b, 0, u2, nullptr);
    // h2 = relu(h @ Wc2 + u2[bt])     (6000 x 256)
    gemm_bt<<<dim3(47, 2), 256, 0, stream>>>(hb, Wc2T, 6000, DH2, DH1,
                                             u2, NOBJ, nullptr, 1, nullptr, h2b);
    // g = mean_n h2
    pool_g<<<BT, DH2, 0, stream>>>(h2b, g);
    // transformer
    qkv_proj<<<BT, DH2, 0, stream>>>(g, Wq, Wk, Wv, q, k, v);
    attn_kernel<<<dim3(100, 4, 2), 128, 0, stream>>>(q, k, v, ctx);
    head_kernel<<<BT, DH2, 0, stream>>>(ctx, g, Wo, ln1g, ln1b, Wf1, bf1,
                                        Wf2, bf2, ln2g, ln2b, Wc, bc, out);
}

// Round 2
// 465.616 us; speedup vs baseline: 1.6921x; 1.6921x over previous
//
#include <hip/hip_runtime.h>
#include <hip/hip_bf16.h>
#include <stdint.h>

typedef unsigned short u16;
typedef __attribute__((ext_vector_type(8))) short short8;
typedef __attribute__((ext_vector_type(4))) float floatx4;
typedef __attribute__((ext_vector_type(4))) unsigned short ushort4_t;

#define BT 200      // B*T
#define NOBJ 30
#define KPAD 4128   // 4097 padded to mult of 32
#define DIN 4097
#define DH1 512
#define DH2 256
#define DFF 512
#define MPAD 6016   // 94 tiles of 64 rows
#define SPAD 256    // 4 tiles of 64 rows for the 200 bt-rows

__device__ __forceinline__ u16 f2bf(float f) {
    union { float f; uint32_t u; } c; c.f = f;
    uint32_t u = c.u;
    u += 0x7FFF + ((u >> 16) & 1);
    return (u16)(u >> 16);
}
__device__ __forceinline__ float bf2f(u16 h) {
    union { uint32_t u; float f; } c; c.u = ((uint32_t)h) << 16;
    return c.f;
}

// async global->LDS DMA, 16B per lane; lds ptr must be wave-uniform (HW adds lane*16)
__device__ __forceinline__ void load16_lds(const u16* g, u16* l) {
    __builtin_amdgcn_global_load_lds(
        (const __attribute__((address_space(1))) void*)g,
        (__attribute__((address_space(3))) void*)l, 16, 0, 0);
}

// ---------------- weight folding ----------------
__global__ void fold_big(const float* __restrict__ W1a, const float* __restrict__ W2a,
                         u16* __restrict__ Wc1T, u16* __restrict__ W2aTs) {
    __shared__ float t1[32][33];
    __shared__ float t2[32][33];
    int kb = blockIdx.x * 32, jb = blockIdx.y * 32;
    int tx = threadIdx.x & 31, ty = threadIdx.x >> 5;   // 32 x 8
    #pragma unroll
    for (int r = 0; r < 32; r += 8) {
        int k = kb + ty + r, j = jb + tx;
        float a = 0.f, b = 0.f;
        if (k < DIN) { a = W1a[k * DH1 + j]; b = W2a[k * DH1 + j]; }
        float bs = b * (1.f / 29.f);
        t1[ty + r][tx] = a - bs;
        t2[ty + r][tx] = bs;
    }
    __syncthreads();
    #pragma unroll
    for (int r = 0; r < 32; r += 8) {
        int j = jb + ty + r, k = kb + tx;
        Wc1T[(size_t)j * KPAD + k]  = f2bf(t1[tx][ty + r]);
        W2aTs[(size_t)j * KPAD + k] = f2bf(t2[tx][ty + r]);
    }
}

__global__ void fold_small(const float* __restrict__ W1b, const float* __restrict__ W2b,
                           u16* __restrict__ Wc2T, u16* __restrict__ W2bTs) {
    int idx = blockIdx.x * 256 + threadIdx.x;   // 256*512 total
    int j = idx >> 9, k = idx & 511;
    float a = W1b[k * DH2 + j];
    float b = W2b[k * DH2 + j] * (1.f / 29.f);
    Wc2T[j * DH1 + k]  = f2bf(a - b);
    W2bTs[j * DH1 + k] = f2bf(b);
}

// ---------------- X concat + bf16 convert + node-sum (float4) ----------------
__global__ void sum_convert(const float* __restrict__ feat, const float* __restrict__ depth,
                            u16* __restrict__ Xb, u16* __restrict__ Sb) {
    int bt = blockIdx.x;
    int k = (blockIdx.y * 256 + threadIdx.x) * 4;
    if (k >= KPAD) return;
    float s0 = 0.f, s1 = 0.f, s2 = 0.f, s3 = 0.f;
    for (int n = 0; n < NOBJ; n++) {
        float4 v;
        if (k + 3 < 4096) {
            v = *(const float4*)(feat + (size_t)(bt * NOBJ + n) * 4096 + k);
        } else {
            v.x = (k == 4096) ? depth[bt * NOBJ + n] : 0.f;
            v.y = 0.f; v.z = 0.f; v.w = 0.f;
        }
        s0 += v.x; s1 += v.y; s2 += v.z; s3 += v.w;
        ushort4_t o; o.x = f2bf(v.x); o.y = f2bf(v.y); o.z = f2bf(v.z); o.w = f2bf(v.w);
        *(ushort4_t*)(Xb + (size_t)(bt * NOBJ + n) * KPAD + k) = o;
    }
    ushort4_t so; so.x = f2bf(s0); so.y = f2bf(s1); so.z = f2bf(s2); so.w = f2bf(s3);
    *(ushort4_t*)(Sb + (size_t)bt * KPAD + k) = so;
}

// ---------------- bf16 MFMA GEMM, B^T layout, 64x128 tile, LDS-DMA staging ----------------
// C[M,N] = A[M,K] @ B^T[N,K] over K-slice blockIdx.z*(kiters*32).
// accum=0: epilogue + row_add[row/row_div][col] + col_add[col]; relu; store f32/bf16
// accum=1: atomicAdd partial into outF (no bias/relu)
// A must be padded to gridDim.y*64 rows; N must be a multiple of 128.
__global__ __launch_bounds__(256) void gemm_bt(
    const u16* __restrict__ A, const u16* __restrict__ B,
    int M, int N, int K, int kiters,
    const float* __restrict__ row_add, int row_div,
    const float* __restrict__ col_add, int relu, int accum,
    float* __restrict__ outF, u16* __restrict__ outB) {
    __shared__ __align__(16) u16 Al[64 * 32];    // 4 KB
    __shared__ __align__(16) u16 Bl[128 * 32];   // 8 KB
    int tid = threadIdx.x;
    int lane = tid & 63, w = tid >> 6;
    int n0 = blockIdx.x * 128, m0 = blockIdx.y * 64;
    int kbeg = blockIdx.z * kiters * 32;
    int kend = min(K, kbeg + kiters * 32);

    // staging source pointers (lane-mapped to LDS-DMA layout: base + lane*16B)
    const u16* ga  = A + (size_t)(m0 + w * 16 + (lane >> 2)) * K + (lane & 3) * 8;
    const u16* gb0 = B + (size_t)(n0 + w * 16 + (lane >> 2)) * K + (lane & 3) * 8;
    const u16* gb1 = gb0 + (size_t)64 * K;
    u16* la  = Al + w * 512;          // wave-uniform LDS chunk bases
    u16* lb0 = Bl + w * 512;
    u16* lb1 = Bl + 2048 + w * 512;

    floatx4 acc[2][4] = {};
    int lrow = lane & 15, ks = (lane >> 4) * 8;
    int wm = (w & 1) * 32, wn = (w >> 1) * 64;

    for (int kb = kbeg; kb < kend; kb += 32) {
        load16_lds(ga + kb, la);
        load16_lds(gb0 + kb, lb0);
        load16_lds(gb1 + kb, lb1);
        __syncthreads();
        short8 af[2], bfv[4];
        #pragma unroll
        for (int i = 0; i < 2; i++)
            af[i] = *(short8*)(Al + (wm + i * 16 + lrow) * 32 + ks);
        #pragma unroll
        for (int j = 0; j < 4; j++)
            bfv[j] = *(short8*)(Bl + (wn + j * 16 + lrow) * 32 + ks);
        #pragma unroll
        for (int i = 0; i < 2; i++)
            #pragma unroll
            for (int j = 0; j < 4; j++)
                acc[i][j] = __builtin_amdgcn_mfma_f32_16x16x32_bf16(af[i], bfv[j], acc[i][j], 0, 0, 0);
        __syncthreads();
    }

    int lcol = lane & 15, rquad = lane >> 4;
    #pragma unroll
    for (int i = 0; i < 2; i++) {
        #pragma unroll
        for (int j = 0; j < 4; j++) {
            #pragma unroll
            for (int r = 0; r < 4; r++) {
                int row = m0 + wm + i * 16 + rquad * 4 + r;
                int col = n0 + wn + j * 16 + lcol;
                if (row < M) {
                    float v = acc[i][j][r];
                    if (accum) {
                        atomicAdd(&outF[(size_t)row * N + col], v);
                    } else {
                        if (row_add) v += row_add[(row / row_div) * N + col];
                        if (col_add) v += col_add[col];
                        if (relu)    v = v > 0.f ? v : 0.f;
                        if (outF) outF[(size_t)row * N + col] = v;
                        if (outB) outB[(size_t)row * N + col] = f2bf(v);
                    }
                }
            }
        }
    }
}

// ---------------- node-sum of h (bf16 512, short8) ----------------
__global__ void sum_h(const u16* __restrict__ hb, u16* __restrict__ Shb) {
    int bt = blockIdx.x, t = threadIdx.x;   // 64 threads
    float acc[8] = {};
    for (int n = 0; n < NOBJ; n++) {
        short8 v = *(const short8*)(hb + (size_t)(bt * NOBJ + n) * DH1 + t * 8);
        #pragma unroll
        for (int e = 0; e < 8; e++) acc[e] += bf2f((u16)v[e]);
    }
    short8 o;
    #pragma unroll
    for (int e = 0; e < 8; e++) o[e] = (short)f2bf(acc[e]);
    *(short8*)(Shb + (size_t)bt * DH1 + t * 8) = o;
}

// ---------------- fused mean-pool + QKV ----------------
__global__ void pool_qkv(const u16* __restrict__ h2b,
                         const float* __restrict__ Wq, const float* __restrict__ Wk,
                         const float* __restrict__ Wv,
                         float* __restrict__ g, float* __restrict__ q,
                         float* __restrict__ k, float* __restrict__ v) {
    __shared__ float gl[DH2];
    int bt = blockIdx.x, j = threadIdx.x;
    float a = 0.f;
    for (int n = 0; n < NOBJ; n++)
        a += bf2f(h2b[(size_t)(bt * NOBJ + n) * DH2 + j]);
    a *= (1.f / 30.f);
    gl[j] = a;
    g[bt * DH2 + j] = a;
    __syncthreads();
    float aq = 0.f, ak = 0.f, av = 0.f;
    for (int kk = 0; kk < DH2; kk++) {
        float x = gl[kk];
        aq += x * Wq[kk * DH2 + j];
        ak += x * Wk[kk * DH2 + j];
        av += x * Wv[kk * DH2 + j];
    }
    q[bt * DH2 + j] = aq;
    k[bt * DH2 + j] = ak;
    v[bt * DH2 + j] = av;
}

// ---------------- attention (per b,h,tq) ----------------
__global__ void attn_kernel(const float* __restrict__ q, const float* __restrict__ kk,
                            const float* __restrict__ vv, float* __restrict__ ctx) {
    int tq = blockIdx.x, h = blockIdx.y, b = blockIdx.z;
    int tid = threadIdx.x;
    __shared__ float qs[64];
    __shared__ float sc[100];
    __shared__ float inv;
    if (tid < 64) qs[tid] = q[(b * 100 + tq) * DH2 + h * 64 + tid];
    __syncthreads();
    if (tid < 100) {
        const float* kr = &kk[(b * 100 + tid) * DH2 + h * 64];
        float s = 0.f;
        for (int d = 0; d < 64; d++) s += qs[d] * kr[d];
        sc[tid] = s * 0.125f;
    }
    __syncthreads();
    if (tid == 0) {
        float mx = -1e30f;
        for (int i = 0; i < 100; i++) mx = fmaxf(mx, sc[i]);
        float sm = 0.f;
        for (int i = 0; i < 100; i++) { float p = __expf(sc[i] - mx); sc[i] = p; sm += p; }
        inv = 1.f / sm;
    }
    __syncthreads();
    if (tid < 64) {
        float o = 0.f;
        for (int s = 0; s < 100; s++) o += sc[s] * vv[(b * 100 + s) * DH2 + h * 64 + tid];
        ctx[(b * 100 + tq) * DH2 + h * 64 + tid] = o * inv;
    }
}

// ---------------- fused head ----------------
__device__ __forceinline__ float block_sum256(float v, volatile float* red) {
    #pragma unroll
    for (int o = 32; o > 0; o >>= 1) v += __shfl_down(v, o);
    int w = threadIdx.x >> 6;
    __syncthreads();
    if ((threadIdx.x & 63) == 0) red[w] = v;
    __syncthreads();
    return red[0] + red[1] + red[2] + red[3];
}

__global__ void head_kernel(const float* __restrict__ ctx, const float* __restrict__ g,
                            const float* __restrict__ Wo,
                            const float* __restrict__ ln1g, const float* __restrict__ ln1b,
                            const float* __restrict__ Wf1, const float* __restrict__ bf1,
                            const float* __restrict__ Wf2, const float* __restrict__ bf2,
                            const float* __restrict__ ln2g, const float* __restrict__ ln2b,
                            const float* __restrict__ Wc, const float* __restrict__ bc,
                            float* __restrict__ out) {
    __shared__ float ctxl[DH2];
    __shared__ float yl[DH2];
    __shared__ float ffl[DFF];
    __shared__ float red[4];
    int row = blockIdx.x, tid = threadIdx.x;
    ctxl[tid] = ctx[row * DH2 + tid];
    __syncthreads();
    float o = 0.f;
    for (int k = 0; k < DH2; k++) o += ctxl[k] * Wo[k * DH2 + tid];
    float t = g[row * DH2 + tid] + o;
    float mu  = block_sum256(t, red) * (1.f / DH2);
    float ex2 = block_sum256(t * t, red) * (1.f / DH2);
    float y = (t - mu) * rsqrtf(ex2 - mu * mu + 1e-5f) * ln1g[tid] + ln1b[tid];
    yl[tid] = y;
    __syncthreads();
    for (int jj = tid; jj < DFF; jj += 256) {
        float a = bf1[jj];
        for (int k = 0; k < DH2; k++) a += yl[k] * Wf1[k * DFF + jj];
        ffl[jj] = a > 0.f ? a : 0.f;
    }
    __syncthreads();
    float o2 = bf2[tid];
    for (int k = 0; k < DFF; k++) o2 += ffl[k] * Wf2[k * DH2 + tid];
    float z0 = y + o2;
    float mu2  = block_sum256(z0, red) * (1.f / DH2);
    float ex22 = block_sum256(z0 * z0, red) * (1.f / DH2);
    float z = (z0 - mu2) * rsqrtf(ex22 - mu2 * mu2 + 1e-5f) * ln2g[tid] + ln2b[tid];
    float logit = block_sum256(z * Wc[tid], red) + bc[0];
    if (tid == 0) {
        out[row]       = 1.f / (1.f + __expf(-logit));
        out[BT + row]  = 0.f;
    }
}

// ---------------- launch ----------------
extern "C" void kernel_launch(void* const* d_in, const int* in_sizes, int n_in,
                              void* d_out, int out_size, void* d_ws, size_t ws_size,
                              hipStream_t stream) {
    const float* feat  = (const float*)d_in[0];
    const float* depth = (const float*)d_in[1];
    const float* W1a = (const float*)d_in[2];
    const float* W2a = (const float*)d_in[3];
    const float* b1a = (const float*)d_in[4];
    const float* W1b = (const float*)d_in[5];
    const float* W2b = (const float*)d_in[6];
    const float* b1b = (const float*)d_in[7];
    const float* Wq  = (const float*)d_in[8];
    const float* Wk  = (const float*)d_in[9];
    const float* Wv  = (const float*)d_in[10];
    const float* Wo  = (const float*)d_in[11];
    const float* ln1g = (const float*)d_in[12];
    const float* ln1b = (const float*)d_in[13];
    const float* Wf1 = (const float*)d_in[14];
    const float* bf1 = (const float*)d_in[15];
    const float* Wf2 = (const float*)d_in[16];
    const float* bf2 = (const float*)d_in[17];
    const float* ln2g = (const float*)d_in[18];
    const float* ln2b = (const float*)d_in[19];
    const float* Wc  = (const float*)d_in[20];
    const float* bc  = (const float*)d_in[21];
    float* out = (float*)d_out;
    char* ws = (char*)d_ws;

    size_t off = 0;
    u16* Xb    = (u16*)(ws + off); off += (size_t)MPAD * KPAD * 2;   // padded to 6016 rows
    u16* Sb    = (u16*)(ws + off); off += (size_t)SPAD * KPAD * 2;   // padded to 256 rows
    u16* Wc1T  = (u16*)(ws + off); off += (size_t)DH1 * KPAD * 2;
    u16* W2aTs = (u16*)(ws + off); off += (size_t)DH1 * KPAD * 2;
    u16* Wc2T  = (u16*)(ws + off); off += (size_t)DH2 * DH1 * 2;
    u16* W2bTs = (u16*)(ws + off); off += (size_t)DH2 * DH1 * 2;
    u16* hb    = (u16*)(ws + off); off += (size_t)MPAD * DH1 * 2;
    u16* Shb   = (u16*)(ws + off); off += (size_t)SPAD * DH1 * 2;
    u16* h2b   = (u16*)(ws + off); off += (size_t)6000 * DH2 * 2;
    float* u   = (float*)(ws + off); off += (size_t)BT * DH1 * 4;
    float* u2  = (float*)(ws + off); off += (size_t)BT * DH2 * 4;
    float* g   = (float*)(ws + off); off += (size_t)BT * DH2 * 4;
    float* q   = (float*)(ws + off); off += (size_t)BT * DH2 * 4;
    float* k   = (float*)(ws + off); off += (size_t)BT * DH2 * 4;
    float* v   = (float*)(ws + off); off += (size_t)BT * DH2 * 4;
    float* ctx = (float*)(ws + off); off += (size_t)BT * DH2 * 4;

    hipMemsetAsync(u,  0, (size_t)BT * DH1 * 4, stream);
    hipMemsetAsync(u2, 0, (size_t)BT * DH2 * 4, stream);

    fold_big<<<dim3(KPAD / 32, DH1 / 32), 256, 0, stream>>>(W1a, W2a, Wc1T, W2aTs);
    fold_small<<<(DH2 * DH1) / 256, 256, 0, stream>>>(W1b, W2b, Wc2T, W2bTs);
    sum_convert<<<dim3(BT, 5), 256, 0, stream>>>(feat, depth, Xb, Sb);

    // u += (S/29) @ W2a  (200x512, K=4128, split-K=6: 22 iters/slice)
    gemm_bt<<<dim3(4, 4, 6), 256, 0, stream>>>(Sb, W2aTs, BT, DH1, KPAD, 22,
                                               nullptr, 1, nullptr, 0, 1, u, nullptr);
    // h = relu(X @ Wc1 + u[bt] + b1a)   (6000x512)
    gemm_bt<<<dim3(4, 94, 1), 256, 0, stream>>>(Xb, Wc1T, 6000, DH1, KPAD, 129,
                                                u, NOBJ, b1a, 1, 0, nullptr, hb);
    sum_h<<<BT, 64, 0, stream>>>(hb, Shb);
    // u2 += (S_h/29) @ W2b  (200x256, K=512, split-K=2: 8 iters/slice)
    gemm_bt<<<dim3(2, 4, 2), 256, 0, stream>>>(Shb, W2bTs, BT, DH2, DH1, 8,
                                               nullptr, 1, nullptr, 0, 1, u2, nullptr);
    // h2 = relu(h @ Wc2 + u2[bt] + b1b)   (6000x256)
    gemm_bt<<<dim3(2, 94, 1), 256, 0, stream>>>(hb, Wc2T, 6000, DH2, DH1, 16,
                                                u2, NOBJ, b1b, 1, 0, nullptr, h2b);
    pool_qkv<<<BT, DH2, 0, stream>>>(h2b, Wq, Wk, Wv, g, q, k, v);
    attn_kernel<<<dim3(100, 4, 2), 128, 0, stream>>>(q, k, v, ctx);
    head_kernel<<<BT, DH2, 0, stream>>>(ctx, g, Wo, ln1g, ln1b, Wf1, bf1,
                                        Wf2, bf2, ln2g, ln2b, Wc, bc, out);
}

// Round 3
// 452.560 us; speedup vs baseline: 1.7409x; 1.0289x over previous
//
#include <hip/hip_runtime.h>
#include <hip/hip_bf16.h>
#include <stdint.h>

typedef unsigned short u16;
typedef __attribute__((ext_vector_type(8))) short short8;
typedef __attribute__((ext_vector_type(4))) float floatx4;
typedef __attribute__((ext_vector_type(4))) unsigned short ushort4_t;

#define BT 200      // B*T
#define NOBJ 30
#define KPAD 4128   // 4097 padded to mult of 32
#define DIN 4097
#define DH1 512
#define DH2 256
#define DFF 512
#define MPAD 6016   // 47 tiles of 128 rows
#define SPAD 256    // 4 tiles of 64 rows for the 200 bt-rows

__device__ __forceinline__ u16 f2bf(float f) {
    union { float f; uint32_t u; } c; c.f = f;
    uint32_t u = c.u;
    u += 0x7FFF + ((u >> 16) & 1);
    return (u16)(u >> 16);
}
__device__ __forceinline__ float bf2f(u16 h) {
    union { uint32_t u; float f; } c; c.u = ((uint32_t)h) << 16;
    return c.f;
}

// async global->LDS DMA, 16B per lane; lds ptr must be wave-uniform (HW adds lane*16)
__device__ __forceinline__ void load16_lds(const u16* g, u16* l) {
    __builtin_amdgcn_global_load_lds(
        (const __attribute__((address_space(1))) void*)g,
        (__attribute__((address_space(3))) void*)l, 16, 0, 0);
}

// ---------------- weight folding ----------------
__global__ void fold_big(const float* __restrict__ W1a, const float* __restrict__ W2a,
                         u16* __restrict__ Wc1T, u16* __restrict__ W2aTs) {
    __shared__ float t1[32][33];
    __shared__ float t2[32][33];
    int kb = blockIdx.x * 32, jb = blockIdx.y * 32;
    int tx = threadIdx.x & 31, ty = threadIdx.x >> 5;   // 32 x 8
    #pragma unroll
    for (int r = 0; r < 32; r += 8) {
        int k = kb + ty + r, j = jb + tx;
        float a = 0.f, b = 0.f;
        if (k < DIN) { a = W1a[k * DH1 + j]; b = W2a[k * DH1 + j]; }
        float bs = b * (1.f / 29.f);
        t1[ty + r][tx] = a - bs;
        t2[ty + r][tx] = bs;
    }
    __syncthreads();
    #pragma unroll
    for (int r = 0; r < 32; r += 8) {
        int j = jb + ty + r, k = kb + tx;
        Wc1T[(size_t)j * KPAD + k]  = f2bf(t1[tx][ty + r]);
        W2aTs[(size_t)j * KPAD + k] = f2bf(t2[tx][ty + r]);
    }
}

__global__ void fold_small(const float* __restrict__ W1b, const float* __restrict__ W2b,
                           u16* __restrict__ Wc2T, u16* __restrict__ W2bTs) {
    int idx = blockIdx.x * 256 + threadIdx.x;   // 256*512 total
    int j = idx >> 9, k = idx & 511;
    float a = W1b[k * DH2 + j];
    float b = W2b[k * DH2 + j] * (1.f / 29.f);
    Wc2T[j * DH1 + k]  = f2bf(a - b);
    W2bTs[j * DH1 + k] = f2bf(b);
}

// ---------------- X concat + bf16 convert + node-sum (float4) ----------------
__global__ void sum_convert(const float* __restrict__ feat, const float* __restrict__ depth,
                            u16* __restrict__ Xb, u16* __restrict__ Sb) {
    int bt = blockIdx.x;
    int k = (blockIdx.y * 256 + threadIdx.x) * 4;
    if (k >= KPAD) return;
    float s0 = 0.f, s1 = 0.f, s2 = 0.f, s3 = 0.f;
    for (int n = 0; n < NOBJ; n++) {
        float4 v;
        if (k + 3 < 4096) {
            v = *(const float4*)(feat + (size_t)(bt * NOBJ + n) * 4096 + k);
        } else {
            v.x = (k == 4096) ? depth[bt * NOBJ + n] : 0.f;
            v.y = 0.f; v.z = 0.f; v.w = 0.f;
        }
        s0 += v.x; s1 += v.y; s2 += v.z; s3 += v.w;
        ushort4_t o; o.x = f2bf(v.x); o.y = f2bf(v.y); o.z = f2bf(v.z); o.w = f2bf(v.w);
        *(ushort4_t*)(Xb + (size_t)(bt * NOBJ + n) * KPAD + k) = o;
    }
    ushort4_t so; so.x = f2bf(s0); so.y = f2bf(s1); so.z = f2bf(s2); so.w = f2bf(s3);
    *(ushort4_t*)(Sb + (size_t)bt * KPAD + k) = so;
}

// -------- 128x128 bf16 MFMA GEMM, B^T, LDS-DMA staging, split-K, atomic f32 out --------
// outAcc[row*N+col] += A[M,K] @ B^T[N,K] over K-slice blockIdx.z.
// A padded to gridDim.y*128 rows; N multiple of 128.
__global__ __launch_bounds__(256) void gemm128(
    const u16* __restrict__ A, const u16* __restrict__ B,
    int M, int N, int K, int kiters,
    float* __restrict__ outAcc) {
    __shared__ __align__(16) u16 Al[128 * 32];   // 8 KB
    __shared__ __align__(16) u16 Bl[128 * 32];   // 8 KB
    int tid = threadIdx.x;
    int lane = tid & 63, w = tid >> 6;
    int n0 = blockIdx.x * 128, m0 = blockIdx.y * 128;
    int kbeg = blockIdx.z * kiters * 32;
    int kend = min(K, kbeg + kiters * 32);

    // staging lane map: chunk c = it*256 + tid; row = c>>2, kchunk = c&3 (8 bf16)
    const u16* gA0 = A + (size_t)(m0 + (tid >> 2)) * K + (tid & 3) * 8;
    const u16* gA1 = A + (size_t)(m0 + 64 + (tid >> 2)) * K + (tid & 3) * 8;
    const u16* gB0 = B + (size_t)(n0 + (tid >> 2)) * K + (tid & 3) * 8;
    const u16* gB1 = B + (size_t)(n0 + 64 + (tid >> 2)) * K + (tid & 3) * 8;
    u16* lA0 = Al + w * 512;           // wave-uniform chunk bases
    u16* lA1 = Al + 2048 + w * 512;
    u16* lB0 = Bl + w * 512;
    u16* lB1 = Bl + 2048 + w * 512;

    floatx4 acc[4][4] = {};
    int lrow = lane & 15, ks = (lane >> 4) * 8;
    int wm = (w & 1) * 64, wn = (w >> 1) * 64;

    for (int kb = kbeg; kb < kend; kb += 32) {
        load16_lds(gA0 + kb, lA0);
        load16_lds(gA1 + kb, lA1);
        load16_lds(gB0 + kb, lB0);
        load16_lds(gB1 + kb, lB1);
        __syncthreads();
        short8 af[4], bfv[4];
        #pragma unroll
        for (int i = 0; i < 4; i++)
            af[i] = *(short8*)(Al + (wm + i * 16 + lrow) * 32 + ks);
        #pragma unroll
        for (int j = 0; j < 4; j++)
            bfv[j] = *(short8*)(Bl + (wn + j * 16 + lrow) * 32 + ks);
        #pragma unroll
        for (int i = 0; i < 4; i++)
            #pragma unroll
            for (int j = 0; j < 4; j++)
                acc[i][j] = __builtin_amdgcn_mfma_f32_16x16x32_bf16(af[i], bfv[j], acc[i][j], 0, 0, 0);
        __syncthreads();
    }

    int lcol = lane & 15, rquad = lane >> 4;
    #pragma unroll
    for (int i = 0; i < 4; i++) {
        #pragma unroll
        for (int j = 0; j < 4; j++) {
            #pragma unroll
            for (int r = 0; r < 4; r++) {
                int row = m0 + wm + i * 16 + rquad * 4 + r;
                int col = n0 + wn + j * 16 + lcol;
                if (row < M)
                    atomicAdd(&outAcc[(size_t)row * N + col], acc[i][j][r]);
            }
        }
    }
}

// -------- 64x128 bf16 MFMA GEMM (small M), split-K, atomic f32 out --------
__global__ __launch_bounds__(256) void gemm64(
    const u16* __restrict__ A, const u16* __restrict__ B,
    int M, int N, int K, int kiters,
    float* __restrict__ outAcc) {
    __shared__ __align__(16) u16 Al[64 * 32];    // 4 KB
    __shared__ __align__(16) u16 Bl[128 * 32];   // 8 KB
    int tid = threadIdx.x;
    int lane = tid & 63, w = tid >> 6;
    int n0 = blockIdx.x * 128, m0 = blockIdx.y * 64;
    int kbeg = blockIdx.z * kiters * 32;
    int kend = min(K, kbeg + kiters * 32);

    const u16* ga  = A + (size_t)(m0 + w * 16 + (lane >> 2)) * K + (lane & 3) * 8;
    const u16* gb0 = B + (size_t)(n0 + w * 16 + (lane >> 2)) * K + (lane & 3) * 8;
    const u16* gb1 = gb0 + (size_t)64 * K;
    u16* la  = Al + w * 512;
    u16* lb0 = Bl + w * 512;
    u16* lb1 = Bl + 2048 + w * 512;

    floatx4 acc[2][4] = {};
    int lrow = lane & 15, ks = (lane >> 4) * 8;
    int wm = (w & 1) * 32, wn = (w >> 1) * 64;

    for (int kb = kbeg; kb < kend; kb += 32) {
        load16_lds(ga + kb, la);
        load16_lds(gb0 + kb, lb0);
        load16_lds(gb1 + kb, lb1);
        __syncthreads();
        short8 af[2], bfv[4];
        #pragma unroll
        for (int i = 0; i < 2; i++)
            af[i] = *(short8*)(Al + (wm + i * 16 + lrow) * 32 + ks);
        #pragma unroll
        for (int j = 0; j < 4; j++)
            bfv[j] = *(short8*)(Bl + (wn + j * 16 + lrow) * 32 + ks);
        #pragma unroll
        for (int i = 0; i < 2; i++)
            #pragma unroll
            for (int j = 0; j < 4; j++)
                acc[i][j] = __builtin_amdgcn_mfma_f32_16x16x32_bf16(af[i], bfv[j], acc[i][j], 0, 0, 0);
        __syncthreads();
    }

    int lcol = lane & 15, rquad = lane >> 4;
    #pragma unroll
    for (int i = 0; i < 2; i++) {
        #pragma unroll
        for (int j = 0; j < 4; j++) {
            #pragma unroll
            for (int r = 0; r < 4; r++) {
                int row = m0 + wm + i * 16 + rquad * 4 + r;
                int col = n0 + wn + j * 16 + lcol;
                if (row < M)
                    atomicAdd(&outAcc[(size_t)row * N + col], acc[i][j][r]);
            }
        }
    }
}

// -------- reduce1: h = relu(hacc + u + b1a) -> bf16; node-sum -> Shb bf16 --------
// grid (BT, DH1/128), 256 threads: 2 rows x 128 cols per pass
__global__ void reduce1(const float* __restrict__ hacc, const float* __restrict__ u,
                        const float* __restrict__ b1a,
                        u16* __restrict__ hb, u16* __restrict__ Shb) {
    __shared__ float sl[128];
    int bt = blockIdx.x, c0 = blockIdx.y * 128;
    int lc = threadIdx.x & 127, rp = threadIdx.x >> 7;
    int col = c0 + lc;
    float ub = u[bt * DH1 + col] + b1a[col];
    float s = 0.f;
    for (int n = rp; n < NOBJ; n += 2) {
        float v = hacc[(size_t)(bt * NOBJ + n) * DH1 + col] + ub;
        v = v > 0.f ? v : 0.f;
        hb[(size_t)(bt * NOBJ + n) * DH1 + col] = f2bf(v);
        s += v;
    }
    if (rp == 0) sl[lc] = s;
    __syncthreads();
    if (rp == 1) Shb[bt * DH1 + col] = f2bf(sl[lc] + s);
}

// -------- reduce2: g = mean_n relu(acc2 + u2 + b1b) --------
// grid (BT, DH2/128), 256 threads
__global__ void reduce2(const float* __restrict__ acc2, const float* __restrict__ u2,
                        const float* __restrict__ b1b, float* __restrict__ g) {
    __shared__ float sl[128];
    int bt = blockIdx.x, c0 = blockIdx.y * 128;
    int lc = threadIdx.x & 127, rp = threadIdx.x >> 7;
    int col = c0 + lc;
    float ub = u2[bt * DH2 + col] + b1b[col];
    float s = 0.f;
    for (int n = rp; n < NOBJ; n += 2) {
        float v = acc2[(size_t)(bt * NOBJ + n) * DH2 + col] + ub;
        s += v > 0.f ? v : 0.f;
    }
    if (rp == 0) sl[lc] = s;
    __syncthreads();
    if (rp == 1) g[bt * DH2 + col] = (sl[lc] + s) * (1.f / 30.f);
}

// ---------------- QKV projections ----------------
__global__ void qkv_proj(const float* __restrict__ g,
                         const float* __restrict__ Wq, const float* __restrict__ Wk,
                         const float* __restrict__ Wv,
                         float* __restrict__ q, float* __restrict__ k, float* __restrict__ v) {
    __shared__ float gl[DH2];
    int bt = blockIdx.x, j = threadIdx.x;
    gl[j] = g[bt * DH2 + j];
    __syncthreads();
    float aq = 0.f, ak = 0.f, av = 0.f;
    for (int kk = 0; kk < DH2; kk++) {
        float x = gl[kk];
        aq += x * Wq[kk * DH2 + j];
        ak += x * Wk[kk * DH2 + j];
        av += x * Wv[kk * DH2 + j];
    }
    q[bt * DH2 + j] = aq;
    k[bt * DH2 + j] = ak;
    v[bt * DH2 + j] = av;
}

// ---------------- attention (per b,h,tq) ----------------
__global__ void attn_kernel(const float* __restrict__ q, const float* __restrict__ kk,
                            const float* __restrict__ vv, float* __restrict__ ctx) {
    int tq = blockIdx.x, h = blockIdx.y, b = blockIdx.z;
    int tid = threadIdx.x;
    __shared__ float qs[64];
    __shared__ float sc[100];
    __shared__ float inv;
    if (tid < 64) qs[tid] = q[(b * 100 + tq) * DH2 + h * 64 + tid];
    __syncthreads();
    if (tid < 100) {
        const float* kr = &kk[(b * 100 + tid) * DH2 + h * 64];
        float s = 0.f;
        for (int d = 0; d < 64; d++) s += qs[d] * kr[d];
        sc[tid] = s * 0.125f;
    }
    __syncthreads();
    if (tid == 0) {
        float mx = -1e30f;
        for (int i = 0; i < 100; i++) mx = fmaxf(mx, sc[i]);
        float sm = 0.f;
        for (int i = 0; i < 100; i++) { float p = __expf(sc[i] - mx); sc[i] = p; sm += p; }
        inv = 1.f / sm;
    }
    __syncthreads();
    if (tid < 64) {
        float o = 0.f;
        for (int s = 0; s < 100; s++) o += sc[s] * vv[(b * 100 + s) * DH2 + h * 64 + tid];
        ctx[(b * 100 + tq) * DH2 + h * 64 + tid] = o * inv;
    }
}

// ---------------- fused head ----------------
__device__ __forceinline__ float block_sum256(float v, volatile float* red) {
    #pragma unroll
    for (int o = 32; o > 0; o >>= 1) v += __shfl_down(v, o);
    int w = threadIdx.x >> 6;
    __syncthreads();
    if ((threadIdx.x & 63) == 0) red[w] = v;
    __syncthreads();
    return red[0] + red[1] + red[2] + red[3];
}

__global__ void head_kernel(const float* __restrict__ ctx, const float* __restrict__ g,
                            const float* __restrict__ Wo,
                            const float* __restrict__ ln1g, const float* __restrict__ ln1b,
                            const float* __restrict__ Wf1, const float* __restrict__ bf1,
                            const float* __restrict__ Wf2, const float* __restrict__ bf2,
                            const float* __restrict__ ln2g, const float* __restrict__ ln2b,
                            const float* __restrict__ Wc, const float* __restrict__ bc,
                            float* __restrict__ out) {
    __shared__ float ctxl[DH2];
    __shared__ float yl[DH2];
    __shared__ float ffl[DFF];
    __shared__ float red[4];
    int row = blockIdx.x, tid = threadIdx.x;
    ctxl[tid] = ctx[row * DH2 + tid];
    __syncthreads();
    float o = 0.f;
    for (int k = 0; k < DH2; k++) o += ctxl[k] * Wo[k * DH2 + tid];
    float t = g[row * DH2 + tid] + o;
    float mu  = block_sum256(t, red) * (1.f / DH2);
    float ex2 = block_sum256(t * t, red) * (1.f / DH2);
    float y = (t - mu) * rsqrtf(ex2 - mu * mu + 1e-5f) * ln1g[tid] + ln1b[tid];
    yl[tid] = y;
    __syncthreads();
    for (int jj = tid; jj < DFF; jj += 256) {
        float a = bf1[jj];
        for (int k = 0; k < DH2; k++) a += yl[k] * Wf1[k * DFF + jj];
        ffl[jj] = a > 0.f ? a : 0.f;
    }
    __syncthreads();
    float o2 = bf2[tid];
    for (int k = 0; k < DFF; k++) o2 += ffl[k] * Wf2[k * DH2 + tid];
    float z0 = y + o2;
    float mu2  = block_sum256(z0, red) * (1.f / DH2);
    float ex22 = block_sum256(z0 * z0, red) * (1.f / DH2);
    float z = (z0 - mu2) * rsqrtf(ex22 - mu2 * mu2 + 1e-5f) * ln2g[tid] + ln2b[tid];
    float logit = block_sum256(z * Wc[tid], red) + bc[0];
    if (tid == 0) {
        out[row]       = 1.f / (1.f + __expf(-logit));
        out[BT + row]  = 0.f;
    }
}

// ---------------- launch ----------------
extern "C" void kernel_launch(void* const* d_in, const int* in_sizes, int n_in,
                              void* d_out, int out_size, void* d_ws, size_t ws_size,
                              hipStream_t stream) {
    const float* feat  = (const float*)d_in[0];
    const float* depth = (const float*)d_in[1];
    const float* W1a = (const float*)d_in[2];
    const float* W2a = (const float*)d_in[3];
    const float* b1a = (const float*)d_in[4];
    const float* W1b = (const float*)d_in[5];
    const float* W2b = (const float*)d_in[6];
    const float* b1b = (const float*)d_in[7];
    const float* Wq  = (const float*)d_in[8];
    const float* Wk  = (const float*)d_in[9];
    const float* Wv  = (const float*)d_in[10];
    const float* Wo  = (const float*)d_in[11];
    const float* ln1g = (const float*)d_in[12];
    const float* ln1b = (const float*)d_in[13];
    const float* Wf1 = (const float*)d_in[14];
    const float* bf1 = (const float*)d_in[15];
    const float* Wf2 = (const float*)d_in[16];
    const float* bf2 = (const float*)d_in[17];
    const float* ln2g = (const float*)d_in[18];
    const float* ln2b = (const float*)d_in[19];
    const float* Wc  = (const float*)d_in[20];
    const float* bc  = (const float*)d_in[21];
    float* out = (float*)d_out;
    char* ws = (char*)d_ws;

    size_t off = 0;
    u16* Xb    = (u16*)(ws + off); off += (size_t)MPAD * KPAD * 2;
    u16* Sb    = (u16*)(ws + off); off += (size_t)SPAD * KPAD * 2;
    u16* Wc1T  = (u16*)(ws + off); off += (size_t)DH1 * KPAD * 2;
    u16* W2aTs = (u16*)(ws + off); off += (size_t)DH1 * KPAD * 2;
    u16* Wc2T  = (u16*)(ws + off); off += (size_t)DH2 * DH1 * 2;
    u16* W2bTs = (u16*)(ws + off); off += (size_t)DH2 * DH1 * 2;
    u16* hb    = (u16*)(ws + off); off += (size_t)MPAD * DH1 * 2;
    u16* Shb   = (u16*)(ws + off); off += (size_t)SPAD * DH1 * 2;
    // contiguous fp32 accumulators (single memset)
    char* accBase = ws + off;
    float* hacc = (float*)(ws + off); off += (size_t)6000 * DH1 * 4;   // 12.3 MB
    float* acc2 = (float*)(ws + off); off += (size_t)6000 * DH2 * 4;   //  6.1 MB
    float* u    = (float*)(ws + off); off += (size_t)BT * DH1 * 4;
    float* u2   = (float*)(ws + off); off += (size_t)BT * DH2 * 4;
    size_t accBytes = (size_t)(ws + off - accBase);
    float* g   = (float*)(ws + off); off += (size_t)BT * DH2 * 4;
    float* q   = (float*)(ws + off); off += (size_t)BT * DH2 * 4;
    float* k   = (float*)(ws + off); off += (size_t)BT * DH2 * 4;
    float* v   = (float*)(ws + off); off += (size_t)BT * DH2 * 4;
    float* ctx = (float*)(ws + off); off += (size_t)BT * DH2 * 4;

    hipMemsetAsync(accBase, 0, accBytes, stream);

    fold_big<<<dim3(KPAD / 32, DH1 / 32), 256, 0, stream>>>(W1a, W2a, Wc1T, W2aTs);
    fold_small<<<(DH2 * DH1) / 256, 256, 0, stream>>>(W1b, W2b, Wc2T, W2bTs);
    sum_convert<<<dim3(BT, 5), 256, 0, stream>>>(feat, depth, Xb, Sb);

    // u += (S/29) @ W2a   (200x512, K=4128, split-K=6: 22 iters)
    gemm64<<<dim3(4, 4, 6), 256, 0, stream>>>(Sb, W2aTs, BT, DH1, KPAD, 22, u);
    // hacc += X @ Wc1     (6000x512, split-K=4: 33 iters)
    gemm128<<<dim3(4, 47, 4), 256, 0, stream>>>(Xb, Wc1T, 6000, DH1, KPAD, 33, hacc);
    // h = relu(hacc + u + b1a) -> hb bf16; Shb = node-sum
    reduce1<<<dim3(BT, 4), 256, 0, stream>>>(hacc, u, b1a, hb, Shb);
    // u2 += (S_h/29) @ W2b  (200x256, K=512, split-K=2: 8 iters)
    gemm64<<<dim3(2, 4, 2), 256, 0, stream>>>(Shb, W2bTs, BT, DH2, DH1, 8, u2);
    // acc2 += h @ Wc2     (6000x256, split-K=4: 4 iters)
    gemm128<<<dim3(2, 47, 4), 256, 0, stream>>>(hb, Wc2T, 6000, DH2, DH1, 4, acc2);
    // g = mean_n relu(acc2 + u2 + b1b)
    reduce2<<<dim3(BT, 2), 256, 0, stream>>>(acc2, u2, b1b, g);

    qkv_proj<<<BT, DH2, 0, stream>>>(g, Wq, Wk, Wv, q, k, v);
    attn_kernel<<<dim3(100, 4, 2), 128, 0, stream>>>(q, k, v, ctx);
    head_kernel<<<BT, DH2, 0, stream>>>(ctx, g, Wo, ln1g, ln1b, Wf1, bf1,
                                        Wf2, bf2, ln2g, ln2b, Wc, bc, out);
}

// Round 4
// 407.512 us; speedup vs baseline: 1.9334x; 1.1105x over previous
//
#include <hip/hip_runtime.h>
#include <hip/hip_bf16.h>
#include <stdint.h>

typedef unsigned short u16;
typedef __attribute__((ext_vector_type(8))) short short8;
typedef __attribute__((ext_vector_type(4))) float floatx4;
typedef __attribute__((ext_vector_type(4))) unsigned short ushort4_t;

#define BT 200      // B*T
#define NOBJ 30
#define KPAD 4160   // 4097 padded to mult of 64
#define DIN 4097
#define DH1 512
#define DH2 256
#define DFF 512
#define MPAD 6016   // 47 tiles of 128 rows
#define SPAD 256
#define NKB (KPAD / 32)        // 130 fold-tile columns
#define NBIG (NKB * (DH1/32))  // 2080 fold_big blocks

__device__ __forceinline__ u16 f2bf(float f) {
    union { float f; uint32_t u; } c; c.f = f;
    uint32_t u = c.u;
    u += 0x7FFF + ((u >> 16) & 1);
    return (u16)(u >> 16);
}
__device__ __forceinline__ float bf2f(u16 h) {
    union { uint32_t u; float f; } c; c.u = ((uint32_t)h) << 16;
    return c.f;
}

// async global->LDS DMA, 16B/lane; LDS dest is wave-uniform base + lane*16
__device__ __forceinline__ void load16_lds(const u16* g, u16* l) {
    __builtin_amdgcn_global_load_lds(
        (const __attribute__((address_space(1))) void*)g,
        (__attribute__((address_space(3))) void*)l, 16, 0, 0);
}

// ---------------- prep: fold_big + fold_small in one launch ----------------
__global__ void prep(const float* __restrict__ W1a, const float* __restrict__ W2a,
                     const float* __restrict__ W1b, const float* __restrict__ W2b,
                     u16* __restrict__ Wc1T, u16* __restrict__ W2aTs,
                     u16* __restrict__ Wc2T, u16* __restrict__ W2bTs) {
    __shared__ float t1[32][33];
    __shared__ float t2[32][33];
    int bid = blockIdx.x;
    if (bid < NBIG) {
        int kb = (bid % NKB) * 32, jb = (bid / NKB) * 32;
        int tx = threadIdx.x & 31, ty = threadIdx.x >> 5;   // 32 x 8
        #pragma unroll
        for (int r = 0; r < 32; r += 8) {
            int k = kb + ty + r, j = jb + tx;
            float a = 0.f, b = 0.f;
            if (k < DIN) { a = W1a[k * DH1 + j]; b = W2a[k * DH1 + j]; }
            float bs = b * (1.f / 29.f);
            t1[ty + r][tx] = a - bs;
            t2[ty + r][tx] = bs;
        }
        __syncthreads();
        #pragma unroll
        for (int r = 0; r < 32; r += 8) {
            int j = jb + ty + r, k = kb + tx;
            Wc1T[(size_t)j * KPAD + k]  = f2bf(t1[tx][ty + r]);
            W2aTs[(size_t)j * KPAD + k] = f2bf(t2[tx][ty + r]);
        }
    } else {
        int idx = (bid - NBIG) * 256 + threadIdx.x;   // 256*512 total
        int j = idx >> 9, k = idx & 511;
        float a = W1b[k * DH2 + j];
        float b = W2b[k * DH2 + j] * (1.f / 29.f);
        Wc2T[j * DH1 + k]  = f2bf(a - b);
        W2bTs[j * DH1 + k] = f2bf(b);
    }
}

// ---------------- X concat + bf16 convert + node-sum (float4) ----------------
__global__ void sum_convert(const float* __restrict__ feat, const float* __restrict__ depth,
                            u16* __restrict__ Xb, u16* __restrict__ Sb) {
    int bt = blockIdx.x;
    int k = (blockIdx.y * 256 + threadIdx.x) * 4;
    if (k >= KPAD) return;
    float s0 = 0.f, s1 = 0.f, s2 = 0.f, s3 = 0.f;
    for (int n = 0; n < NOBJ; n++) {
        float4 v;
        if (k + 3 < 4096) {
            v = *(const float4*)(feat + (size_t)(bt * NOBJ + n) * 4096 + k);
        } else {
            v.x = (k == 4096) ? depth[bt * NOBJ + n] : 0.f;
            v.y = 0.f; v.z = 0.f; v.w = 0.f;
        }
        s0 += v.x; s1 += v.y; s2 += v.z; s3 += v.w;
        ushort4_t o; o.x = f2bf(v.x); o.y = f2bf(v.y); o.z = f2bf(v.z); o.w = f2bf(v.w);
        *(ushort4_t*)(Xb + (size_t)(bt * NOBJ + n) * KPAD + k) = o;
    }
    ushort4_t so; so.x = f2bf(s0); so.y = f2bf(s1); so.z = f2bf(s2); so.w = f2bf(s3);
    *(ushort4_t*)(Sb + (size_t)bt * KPAD + k) = so;
}

// ======== 128x128 bf16 MFMA GEMM, B^T, BK=64, XOR-swizzled LDS-DMA staging ========
// mode 0: atomicAdd partial into outF (split-K)
// mode 1: epilogue v += row_add[(row/row_div)*N+col] + col_add[col]; relu; store f32
// K multiple of 64; A padded to gridDim.y*128 rows; N multiple of 128.
__global__ __launch_bounds__(256) void gemm128(
    const u16* __restrict__ A, const u16* __restrict__ B,
    int M, int N, int K, int kiters, int mode,
    const float* __restrict__ row_add, int row_div,
    const float* __restrict__ col_add,
    float* __restrict__ outF) {
    __shared__ __align__(16) u16 Al[128 * 64];   // 16 KB
    __shared__ __align__(16) u16 Bl[128 * 64];   // 16 KB
    int tid = threadIdx.x;
    int lane = tid & 63, w = tid >> 6;
    int n0 = blockIdx.x * 128, m0 = blockIdx.y * 128;
    int kbeg = blockIdx.z * kiters * 64;
    int kend = min(K, kbeg + kiters * 64);

    // staging: chunk c = it*256+tid -> logical (row=c>>3, kslot=c&7); source column
    // is swizzled kphys = kslot ^ (row&7) so ds_read banks spread fully.
    int srow = tid >> 3, kslot = tid & 7;
    floatx4 acc[4][4] = {};
    int lrow = lane & 15, q = lane >> 4;
    int wm = (w & 1) * 64, wn = (w >> 1) * 64;
    int swzbase = lrow & 7;

    for (int kb = kbeg; kb < kend; kb += 64) {
        #pragma unroll
        for (int it = 0; it < 4; it++) {
            int row = it * 32 + srow;                  // c>>3 with c=it*256+tid
            int kph = kslot ^ (row & 7);
            load16_lds(A + (size_t)(m0 + row) * K + kb + kph * 8,
                       Al + it * 2048 + w * 512);
            load16_lds(B + (size_t)(n0 + row) * K + kb + kph * 8,
                       Bl + it * 2048 + w * 512);
        }
        __syncthreads();
        #pragma unroll
        for (int h = 0; h < 2; h++) {
            int ci = h * 4 + q;
            int so = (ci ^ swzbase) * 8;
            short8 af[4], bfv[4];
            #pragma unroll
            for (int i = 0; i < 4; i++)
                af[i] = *(short8*)(Al + (wm + i * 16 + lrow) * 64 + so);
            #pragma unroll
            for (int j = 0; j < 4; j++)
                bfv[j] = *(short8*)(Bl + (wn + j * 16 + lrow) * 64 + so);
            #pragma unroll
            for (int i = 0; i < 4; i++)
                #pragma unroll
                for (int j = 0; j < 4; j++)
                    acc[i][j] = __builtin_amdgcn_mfma_f32_16x16x32_bf16(af[i], bfv[j], acc[i][j], 0, 0, 0);
        }
        __syncthreads();
    }

    #pragma unroll
    for (int i = 0; i < 4; i++) {
        #pragma unroll
        for (int j = 0; j < 4; j++) {
            #pragma unroll
            for (int r = 0; r < 4; r++) {
                int row = m0 + wm + i * 16 + q * 4 + r;
                int col = n0 + wn + j * 16 + lrow;
                if (row < M) {
                    float v = acc[i][j][r];
                    if (mode == 0) {
                        atomicAdd(&outF[(size_t)row * N + col], v);
                    } else {
                        v += row_add[(row / row_div) * N + col] + col_add[col];
                        v = v > 0.f ? v : 0.f;
                        outF[(size_t)row * N + col] = v;
                    }
                }
            }
        }
    }
}

// ======== 64x128 bf16 MFMA GEMM (small M), BK=64, swizzled, split-K atomic ========
__global__ __launch_bounds__(256) void gemm64(
    const u16* __restrict__ A, const u16* __restrict__ B,
    int M, int N, int K, int kiters,
    float* __restrict__ outAcc) {
    __shared__ __align__(16) u16 Al[64 * 64];    // 8 KB
    __shared__ __align__(16) u16 Bl[128 * 64];   // 16 KB
    int tid = threadIdx.x;
    int lane = tid & 63, w = tid >> 6;
    int n0 = blockIdx.x * 128, m0 = blockIdx.y * 64;
    int kbeg = blockIdx.z * kiters * 64;
    int kend = min(K, kbeg + kiters * 64);

    int srow = tid >> 3, kslot = tid & 7;
    floatx4 acc[2][4] = {};
    int lrow = lane & 15, q = lane >> 4;
    int wm = (w & 1) * 32, wn = (w >> 1) * 64;
    int swzbase = lrow & 7;

    for (int kb = kbeg; kb < kend; kb += 64) {
        #pragma unroll
        for (int it = 0; it < 2; it++) {
            int row = it * 32 + srow;
            int kph = kslot ^ (row & 7);
            load16_lds(A + (size_t)(m0 + row) * K + kb + kph * 8,
                       Al + it * 2048 + w * 512);
        }
        #pragma unroll
        for (int it = 0; it < 4; it++) {
            int row = it * 32 + srow;
            int kph = kslot ^ (row & 7);
            load16_lds(B + (size_t)(n0 + row) * K + kb + kph * 8,
                       Bl + it * 2048 + w * 512);
        }
        __syncthreads();
        #pragma unroll
        for (int h = 0; h < 2; h++) {
            int ci = h * 4 + q;
            int so = (ci ^ swzbase) * 8;
            short8 af[2], bfv[4];
            #pragma unroll
            for (int i = 0; i < 2; i++)
                af[i] = *(short8*)(Al + (wm + i * 16 + lrow) * 64 + so);
            #pragma unroll
            for (int j = 0; j < 4; j++)
                bfv[j] = *(short8*)(Bl + (wn + j * 16 + lrow) * 64 + so);
            #pragma unroll
            for (int i = 0; i < 2; i++)
                #pragma unroll
                for (int j = 0; j < 4; j++)
                    acc[i][j] = __builtin_amdgcn_mfma_f32_16x16x32_bf16(af[i], bfv[j], acc[i][j], 0, 0, 0);
        }
        __syncthreads();
    }

    #pragma unroll
    for (int i = 0; i < 2; i++) {
        #pragma unroll
        for (int j = 0; j < 4; j++) {
            #pragma unroll
            for (int r = 0; r < 4; r++) {
                int row = m0 + wm + i * 16 + q * 4 + r;
                int col = n0 + wn + j * 16 + lrow;
                if (row < M)
                    atomicAdd(&outAcc[(size_t)row * N + col], acc[i][j][r]);
            }
        }
    }
}

// -------- reduce1: h = relu(hacc + u + b1a) -> bf16; node-sum -> Shb bf16 --------
__global__ void reduce1(const float* __restrict__ hacc, const float* __restrict__ u,
                        const float* __restrict__ b1a,
                        u16* __restrict__ hb, u16* __restrict__ Shb) {
    __shared__ float sl[128];
    int bt = blockIdx.x, c0 = blockIdx.y * 128;
    int lc = threadIdx.x & 127, rp = threadIdx.x >> 7;
    int col = c0 + lc;
    float ub = u[bt * DH1 + col] + b1a[col];
    float s = 0.f;
    for (int n = rp; n < NOBJ; n += 2) {
        float v = hacc[(size_t)(bt * NOBJ + n) * DH1 + col] + ub;
        v = v > 0.f ? v : 0.f;
        hb[(size_t)(bt * NOBJ + n) * DH1 + col] = f2bf(v);
        s += v;
    }
    if (rp == 0) sl[lc] = s;
    __syncthreads();
    if (rp == 1) Shb[bt * DH1 + col] = f2bf(sl[lc] + s);
}

// -------- reduce2 + QKV fused: g = mean_n h2; q,k,v = g @ Wq/Wk/Wv --------
__global__ void reduce2_qkv(const float* __restrict__ h2,
                            const float* __restrict__ Wq, const float* __restrict__ Wk,
                            const float* __restrict__ Wv,
                            float* __restrict__ g, float* __restrict__ q,
                            float* __restrict__ k, float* __restrict__ v) {
    __shared__ float gl[DH2];
    int bt = blockIdx.x, j = threadIdx.x;
    float a = 0.f;
    for (int n = 0; n < NOBJ; n++)
        a += h2[(size_t)(bt * NOBJ + n) * DH2 + j];
    a *= (1.f / 30.f);
    gl[j] = a;
    g[bt * DH2 + j] = a;
    __syncthreads();
    float aq = 0.f, ak = 0.f, av = 0.f;
    for (int kk = 0; kk < DH2; kk++) {
        float x = gl[kk];
        aq += x * Wq[kk * DH2 + j];
        ak += x * Wk[kk * DH2 + j];
        av += x * Wv[kk * DH2 + j];
    }
    q[bt * DH2 + j] = aq;
    k[bt * DH2 + j] = ak;
    v[bt * DH2 + j] = av;
}

// -------- fused attention + Wo + LN1 + FFN + LN2 + classifier (block per row) --------
__device__ __forceinline__ float block_sum256(float v, volatile float* red) {
    #pragma unroll
    for (int o = 32; o > 0; o >>= 1) v += __shfl_down(v, o);
    int w = threadIdx.x >> 6;
    __syncthreads();
    if ((threadIdx.x & 63) == 0) red[w] = v;
    __syncthreads();
    return red[0] + red[1] + red[2] + red[3];
}

__global__ void attn_head(const float* __restrict__ qg, const float* __restrict__ kg,
                          const float* __restrict__ vg, const float* __restrict__ g,
                          const float* __restrict__ Wo,
                          const float* __restrict__ ln1g, const float* __restrict__ ln1b,
                          const float* __restrict__ Wf1, const float* __restrict__ bf1,
                          const float* __restrict__ Wf2, const float* __restrict__ bf2,
                          const float* __restrict__ ln2g, const float* __restrict__ ln2b,
                          const float* __restrict__ Wc, const float* __restrict__ bc,
                          float* __restrict__ out) {
    __shared__ float ql[DH2];
    __shared__ float scl[4][128];
    __shared__ float ctxl[DH2];
    __shared__ float yl[DH2];
    __shared__ float ffl[DFF];
    __shared__ float red[4];
    int row = blockIdx.x, tid = threadIdx.x;
    int b = (row >= 100) ? 1 : 0;
    int base = b * 100;
    ql[tid] = qg[row * DH2 + tid];
    __syncthreads();

    // scores: 4 heads x 100 keys
    for (int p = tid; p < 512; p += 256) {
        int h = p >> 7, s = p & 127;
        if (s < 100) {
            const float* kr = kg + (size_t)(base + s) * DH2 + h * 64;
            float a = 0.f;
            #pragma unroll 8
            for (int d = 0; d < 64; d++) a += ql[h * 64 + d] * kr[d];
            scl[h][s] = a * 0.125f;
        }
    }
    __syncthreads();

    // softmax: wave w handles head w
    {
        int w = tid >> 6, lane = tid & 63;
        int s2 = 64 + lane;
        float a  = scl[w][lane];
        float b2 = (s2 < 100) ? scl[w][s2] : -1e30f;
        float m = fmaxf(a, b2);
        #pragma unroll
        for (int o = 32; o > 0; o >>= 1) m = fmaxf(m, __shfl_down(m, o));
        m = __shfl(m, 0);
        float e1 = __expf(a - m);
        float e2 = (s2 < 100) ? __expf(b2 - m) : 0.f;
        float sm = e1 + e2;
        #pragma unroll
        for (int o = 32; o > 0; o >>= 1) sm += __shfl_down(sm, o);
        sm = __shfl(sm, 0);
        float r = 1.f / sm;
        scl[w][lane] = e1 * r;
        if (s2 < 100) scl[w][s2] = e2 * r;
    }
    __syncthreads();

    // PV: ctx col = tid (= h*64+d)
    {
        int h = tid >> 6;
        float o = 0.f;
        for (int s = 0; s < 100; s++)
            o += scl[h][s] * vg[(size_t)(base + s) * DH2 + tid];
        ctxl[tid] = o;
    }
    __syncthreads();

    // Wo projection + residual
    float o = 0.f;
    for (int kk = 0; kk < DH2; kk++) o += ctxl[kk] * Wo[kk * DH2 + tid];
    float t = g[row * DH2 + tid] + o;
    float mu  = block_sum256(t, red) * (1.f / DH2);
    float ex2 = block_sum256(t * t, red) * (1.f / DH2);
    float y = (t - mu) * rsqrtf(ex2 - mu * mu + 1e-5f) * ln1g[tid] + ln1b[tid];
    yl[tid] = y;
    __syncthreads();
    for (int jj = tid; jj < DFF; jj += 256) {
        float a = bf1[jj];
        for (int kk = 0; kk < DH2; kk++) a += yl[kk] * Wf1[kk * DFF + jj];
        ffl[jj] = a > 0.f ? a : 0.f;
    }
    __syncthreads();
    float o2 = bf2[tid];
    for (int kk = 0; kk < DFF; kk++) o2 += ffl[kk] * Wf2[kk * DH2 + tid];
    float z0 = y + o2;
    float mu2  = block_sum256(z0, red) * (1.f / DH2);
    float ex22 = block_sum256(z0 * z0, red) * (1.f / DH2);
    float z = (z0 - mu2) * rsqrtf(ex22 - mu2 * mu2 + 1e-5f) * ln2g[tid] + ln2b[tid];
    float logit = block_sum256(z * Wc[tid], red) + bc[0];
    if (tid == 0) {
        out[row]      = 1.f / (1.f + __expf(-logit));
        out[BT + row] = 0.f;
    }
}

// ---------------- launch ----------------
extern "C" void kernel_launch(void* const* d_in, const int* in_sizes, int n_in,
                              void* d_out, int out_size, void* d_ws, size_t ws_size,
                              hipStream_t stream) {
    const float* feat  = (const float*)d_in[0];
    const float* depth = (const float*)d_in[1];
    const float* W1a = (const float*)d_in[2];
    const float* W2a = (const float*)d_in[3];
    const float* b1a = (const float*)d_in[4];
    const float* W1b = (const float*)d_in[5];
    const float* W2b = (const float*)d_in[6];
    const float* b1b = (const float*)d_in[7];
    const float* Wq  = (const float*)d_in[8];
    const float* Wk  = (const float*)d_in[9];
    const float* Wv  = (const float*)d_in[10];
    const float* Wo  = (const float*)d_in[11];
    const float* ln1g = (const float*)d_in[12];
    const float* ln1b = (const float*)d_in[13];
    const float* Wf1 = (const float*)d_in[14];
    const float* bf1 = (const float*)d_in[15];
    const float* Wf2 = (const float*)d_in[16];
    const float* bf2 = (const float*)d_in[17];
    const float* ln2g = (const float*)d_in[18];
    const float* ln2b = (const float*)d_in[19];
    const float* Wc  = (const float*)d_in[20];
    const float* bc  = (const float*)d_in[21];
    float* out = (float*)d_out;
    char* ws = (char*)d_ws;

    size_t off = 0;
    u16* Xb    = (u16*)(ws + off); off += (size_t)MPAD * KPAD * 2;   // 50.1 MB
    u16* Sb    = (u16*)(ws + off); off += (size_t)SPAD * KPAD * 2;
    u16* Wc1T  = (u16*)(ws + off); off += (size_t)DH1 * KPAD * 2;
    u16* W2aTs = (u16*)(ws + off); off += (size_t)DH1 * KPAD * 2;
    u16* Wc2T  = (u16*)(ws + off); off += (size_t)DH2 * DH1 * 2;
    u16* W2bTs = (u16*)(ws + off); off += (size_t)DH2 * DH1 * 2;
    u16* hb    = (u16*)(ws + off); off += (size_t)MPAD * DH1 * 2;
    u16* Shb   = (u16*)(ws + off); off += (size_t)SPAD * DH1 * 2;
    // contiguous zero-init region: hacc + u + u2
    char* zBase = ws + off;
    float* hacc = (float*)(ws + off); off += (size_t)6000 * DH1 * 4;  // 12.3 MB
    float* u    = (float*)(ws + off); off += (size_t)BT * DH1 * 4;
    float* u2   = (float*)(ws + off); off += (size_t)BT * DH2 * 4;
    size_t zBytes = (size_t)(ws + off - zBase);
    float* g   = (float*)(ws + off); off += (size_t)BT * DH2 * 4;
    float* q   = (float*)(ws + off); off += (size_t)BT * DH2 * 4;
    float* k   = (float*)(ws + off); off += (size_t)BT * DH2 * 4;
    float* v   = (float*)(ws + off); off += (size_t)BT * DH2 * 4;
    // h2 (6000x256 f32, 6.1 MB) aliases Xb, which is dead once gemm128(hacc) completes
    float* h2  = (float*)Xb;

    hipMemsetAsync(zBase, 0, zBytes, stream);
    prep<<<NBIG + 512, 256, 0, stream>>>(W1a, W2a, W1b, W2b, Wc1T, W2aTs, Wc2T, W2bTs);
    sum_convert<<<dim3(BT, 5), 256, 0, stream>>>(feat, depth, Xb, Sb);

    // u += (S/29) @ W2a   (200x512, K=4160: 65 chunks, z=6 x 11)
    gemm64<<<dim3(4, 4, 6), 256, 0, stream>>>(Sb, W2aTs, BT, DH1, KPAD, 11, u);
    // hacc += X @ Wc1     (6000x512, z=2 x 33 chunks)
    gemm128<<<dim3(4, 47, 2), 256, 0, stream>>>(Xb, Wc1T, 6000, DH1, KPAD, 33, 0,
                                                nullptr, 1, nullptr, hacc);
    // h = relu(hacc + u + b1a) -> hb bf16; Shb = node-sum
    reduce1<<<dim3(BT, 4), 256, 0, stream>>>(hacc, u, b1a, hb, Shb);
    // u2 += (S_h/29) @ W2b  (200x256, K=512: 8 chunks, z=2 x 4)
    gemm64<<<dim3(2, 4, 2), 256, 0, stream>>>(Shb, W2bTs, BT, DH2, DH1, 4, u2);
    // h2 = relu(hb @ Wc2 + u2[bt] + b1b)  (6000x256, full-K epilogue store)
    gemm128<<<dim3(2, 47, 1), 256, 0, stream>>>(hb, Wc2T, 6000, DH2, DH1, 8, 1,
                                                u2, NOBJ, b1b, h2);
    // g = mean_n h2; qkv
    reduce2_qkv<<<BT, DH2, 0, stream>>>(h2, Wq, Wk, Wv, g, q, k, v);
    // attention + transformer tail + classifier
    attn_head<<<BT, DH2, 0, stream>>>(q, k, v, g, Wo, ln1g, ln1b, Wf1, bf1,
                                      Wf2, bf2, ln2g, ln2b, Wc, bc, out);
}

// Round 5
// 398.568 us; speedup vs baseline: 1.9768x; 1.0224x over previous
//
#include <hip/hip_runtime.h>
#include <hip/hip_bf16.h>
#include <stdint.h>

typedef unsigned short u16;
typedef __attribute__((ext_vector_type(8))) short short8;
typedef __attribute__((ext_vector_type(4))) float floatx4;
typedef __attribute__((ext_vector_type(4))) unsigned short ushort4_t;

#define BT 200      // B*T
#define NOBJ 30
#define KPAD 4160   // 4097 padded to mult of 64
#define DIN 4097
#define DH1 512
#define DH2 256
#define DFF 512
#define MPAD 6016   // 47 tiles of 128 rows
#define SPAD 256
#define NKB (KPAD / 32)        // 130 fold-tile columns
#define NBIG (NKB * (DH1/32))  // 2080 fold_big blocks
#define NSMALL 512             // fold_small blocks
#define NCONV 1000             // sum_convert blocks (BT x 5)

__device__ __forceinline__ u16 f2bf(float f) {
    union { float f; uint32_t u; } c; c.f = f;
    uint32_t u = c.u;
    u += 0x7FFF + ((u >> 16) & 1);
    return (u16)(u >> 16);
}
__device__ __forceinline__ float bf2f(u16 h) {
    union { uint32_t u; float f; } c; c.u = ((uint32_t)h) << 16;
    return c.f;
}

// async global->LDS DMA, 16B/lane; LDS dest is wave-uniform base + lane*16
__device__ __forceinline__ void load16_lds(const u16* g, u16* l) {
    __builtin_amdgcn_global_load_lds(
        (const __attribute__((address_space(1))) void*)g,
        (__attribute__((address_space(3))) void*)l, 16, 0, 0);
}

// ======== prep_all: fold_big | fold_small | sum_convert in one launch ========
__global__ void prep_all(const float* __restrict__ W1a, const float* __restrict__ W2a,
                         const float* __restrict__ W1b, const float* __restrict__ W2b,
                         const float* __restrict__ feat, const float* __restrict__ depth,
                         u16* __restrict__ Wc1T, u16* __restrict__ W2aTs,
                         u16* __restrict__ Wc2T, u16* __restrict__ W2bTs,
                         u16* __restrict__ Xb, u16* __restrict__ Sb) {
    __shared__ float t1[32][33];
    __shared__ float t2[32][33];
    int bid = blockIdx.x;
    if (bid < NBIG) {
        int kb = (bid % NKB) * 32, jb = (bid / NKB) * 32;
        int tx = threadIdx.x & 31, ty = threadIdx.x >> 5;   // 32 x 8
        #pragma unroll
        for (int r = 0; r < 32; r += 8) {
            int k = kb + ty + r, j = jb + tx;
            float a = 0.f, b = 0.f;
            if (k < DIN) { a = W1a[k * DH1 + j]; b = W2a[k * DH1 + j]; }
            float bs = b * (1.f / 29.f);
            t1[ty + r][tx] = a - bs;
            t2[ty + r][tx] = bs;
        }
        __syncthreads();
        #pragma unroll
        for (int r = 0; r < 32; r += 8) {
            int j = jb + ty + r, k = kb + tx;
            Wc1T[(size_t)j * KPAD + k]  = f2bf(t1[tx][ty + r]);
            W2aTs[(size_t)j * KPAD + k] = f2bf(t2[tx][ty + r]);
        }
    } else if (bid < NBIG + NSMALL) {
        int idx = (bid - NBIG) * 256 + threadIdx.x;   // 256*512 total
        int j = idx >> 9, k = idx & 511;
        float a = W1b[k * DH2 + j];
        float b = W2b[k * DH2 + j] * (1.f / 29.f);
        Wc2T[j * DH1 + k]  = f2bf(a - b);
        W2bTs[j * DH1 + k] = f2bf(b);
    } else {
        int cid = bid - NBIG - NSMALL;
        int bt = cid / 5;
        int k = ((cid % 5) * 256 + threadIdx.x) * 4;
        if (k >= KPAD) return;
        float s0 = 0.f, s1 = 0.f, s2 = 0.f, s3 = 0.f;
        for (int n = 0; n < NOBJ; n++) {
            float4 v;
            if (k + 3 < 4096) {
                v = *(const float4*)(feat + (size_t)(bt * NOBJ + n) * 4096 + k);
            } else {
                v.x = (k == 4096) ? depth[bt * NOBJ + n] : 0.f;
                v.y = 0.f; v.z = 0.f; v.w = 0.f;
            }
            s0 += v.x; s1 += v.y; s2 += v.z; s3 += v.w;
            ushort4_t o; o.x = f2bf(v.x); o.y = f2bf(v.y); o.z = f2bf(v.z); o.w = f2bf(v.w);
            *(ushort4_t*)(Xb + (size_t)(bt * NOBJ + n) * KPAD + k) = o;
        }
        ushort4_t so; so.x = f2bf(s0); so.y = f2bf(s1); so.z = f2bf(s2); so.w = f2bf(s3);
        *(ushort4_t*)(Sb + (size_t)bt * KPAD + k) = so;
    }
}

// ======== gemmA: 128x128 bf16 MFMA, BK=64, swizzled, split-K atomic ========
// seg0 (564 blocks): hacc += Xb @ Wc1T   (M=6000, N=512, z=3 x 22 chunks)
// seg1 ( 48 blocks): u    += Sb @ W2aTs  (M=200,  N=512, z=6 x 11 chunks)
__global__ __launch_bounds__(256) void gemmA(
    const u16* __restrict__ Xb, const u16* __restrict__ Wc1T,
    const u16* __restrict__ Sb, const u16* __restrict__ W2aTs,
    float* __restrict__ hacc, float* __restrict__ uOut) {
    __shared__ __align__(16) u16 Al[128 * 64];   // 16 KB
    __shared__ __align__(16) u16 Bl[128 * 64];   // 16 KB
    int bid = blockIdx.x;
    const u16 *A, *B;
    float* outF;
    int m0, n0, kbeg, kend, M;
    if (bid < 564) {
        int x = bid & 3, y = (bid >> 2) % 47, z = bid / 188;
        A = Xb; B = Wc1T; outF = hacc; M = 6000;
        m0 = y * 128; n0 = x * 128;
        kbeg = z * 22 * 64; kend = min(KPAD, kbeg + 22 * 64);
    } else {
        int rem = bid - 564;
        int x = rem & 3, y = (rem >> 2) & 1, z = rem >> 3;
        A = Sb; B = W2aTs; outF = uOut; M = BT;
        m0 = y * 128; n0 = x * 128;
        kbeg = z * 11 * 64; kend = min(KPAD, kbeg + 11 * 64);
    }
    const int N = DH1;
    int tid = threadIdx.x;
    int lane = tid & 63, w = tid >> 6;
    int srow = tid >> 3, kslot = tid & 7;
    floatx4 acc[4][4] = {};
    int lrow = lane & 15, q = lane >> 4;
    int wm = (w & 1) * 64, wn = (w >> 1) * 64;
    int swzbase = lrow & 7;

    for (int kb = kbeg; kb < kend; kb += 64) {
        #pragma unroll
        for (int it = 0; it < 4; it++) {
            int row = it * 32 + srow;
            int kph = kslot ^ (row & 7);
            load16_lds(A + (size_t)(m0 + row) * KPAD + kb + kph * 8,
                       Al + it * 2048 + w * 512);
            load16_lds(B + (size_t)(n0 + row) * KPAD + kb + kph * 8,
                       Bl + it * 2048 + w * 512);
        }
        __syncthreads();
        #pragma unroll
        for (int h = 0; h < 2; h++) {
            int ci = h * 4 + q;
            int so = (ci ^ swzbase) * 8;
            short8 af[4], bfv[4];
            #pragma unroll
            for (int i = 0; i < 4; i++)
                af[i] = *(short8*)(Al + (wm + i * 16 + lrow) * 64 + so);
            #pragma unroll
            for (int j = 0; j < 4; j++)
                bfv[j] = *(short8*)(Bl + (wn + j * 16 + lrow) * 64 + so);
            #pragma unroll
            for (int i = 0; i < 4; i++)
                #pragma unroll
                for (int j = 0; j < 4; j++)
                    acc[i][j] = __builtin_amdgcn_mfma_f32_16x16x32_bf16(af[i], bfv[j], acc[i][j], 0, 0, 0);
        }
        __syncthreads();
    }

    #pragma unroll
    for (int i = 0; i < 4; i++)
        #pragma unroll
        for (int j = 0; j < 4; j++)
            #pragma unroll
            for (int r = 0; r < 4; r++) {
                int row = m0 + wm + i * 16 + q * 4 + r;
                int col = n0 + wn + j * 16 + lrow;
                if (row < M)
                    atomicAdd(&outF[(size_t)row * N + col], acc[i][j][r]);
            }
}

// ======== gemmB: 64x128 bf16 MFMA, BK=64, swizzled, split-K atomic, K=512 ========
// seg0 (376 blocks): hacc2 += hb @ Wc2T   (M=6000, z=2 x 4 chunks)
// seg1 ( 16 blocks): u2    += Shb @ W2bTs (M=200,  z=2 x 4 chunks)
__global__ __launch_bounds__(256) void gemmB(
    const u16* __restrict__ hb, const u16* __restrict__ Wc2T,
    const u16* __restrict__ Shb, const u16* __restrict__ W2bTs,
    float* __restrict__ hacc2, float* __restrict__ u2Out) {
    __shared__ __align__(16) u16 Al[64 * 64];    // 8 KB
    __shared__ __align__(16) u16 Bl[128 * 64];   // 16 KB
    int bid = blockIdx.x;
    const u16 *A, *B;
    float* outF;
    int m0, n0, kbeg, M;
    if (bid < 376) {
        int x = bid & 1, y = (bid >> 1) % 94, z = bid / 188;
        A = hb; B = Wc2T; outF = hacc2; M = 6000;
        m0 = y * 64; n0 = x * 128; kbeg = z * 4 * 64;
    } else {
        int rem = bid - 376;
        int x = rem & 1, y = (rem >> 1) & 3, z = rem >> 3;
        A = Shb; B = W2bTs; outF = u2Out; M = BT;
        m0 = y * 64; n0 = x * 128; kbeg = z * 4 * 64;
    }
    int kend = kbeg + 4 * 64;
    const int N = DH2, K = DH1;
    int tid = threadIdx.x;
    int lane = tid & 63, w = tid >> 6;
    int srow = tid >> 3, kslot = tid & 7;
    floatx4 acc[2][4] = {};
    int lrow = lane & 15, q = lane >> 4;
    int wm = (w & 1) * 32, wn = (w >> 1) * 64;
    int swzbase = lrow & 7;

    for (int kb = kbeg; kb < kend; kb += 64) {
        #pragma unroll
        for (int it = 0; it < 2; it++) {
            int row = it * 32 + srow;
            int kph = kslot ^ (row & 7);
            load16_lds(A + (size_t)(m0 + row) * K + kb + kph * 8,
                       Al + it * 2048 + w * 512);
        }
        #pragma unroll
        for (int it = 0; it < 4; it++) {
            int row = it * 32 + srow;
            int kph = kslot ^ (row & 7);
            load16_lds(B + (size_t)(n0 + row) * K + kb + kph * 8,
                       Bl + it * 2048 + w * 512);
        }
        __syncthreads();
        #pragma unroll
        for (int h = 0; h < 2; h++) {
            int ci = h * 4 + q;
            int so = (ci ^ swzbase) * 8;
            short8 af[2], bfv[4];
            #pragma unroll
            for (int i = 0; i < 2; i++)
                af[i] = *(short8*)(Al + (wm + i * 16 + lrow) * 64 + so);
            #pragma unroll
            for (int j = 0; j < 4; j++)
                bfv[j] = *(short8*)(Bl + (wn + j * 16 + lrow) * 64 + so);
            #pragma unroll
            for (int i = 0; i < 2; i++)
                #pragma unroll
                for (int j = 0; j < 4; j++)
                    acc[i][j] = __builtin_amdgcn_mfma_f32_16x16x32_bf16(af[i], bfv[j], acc[i][j], 0, 0, 0);
        }
        __syncthreads();
    }

    #pragma unroll
    for (int i = 0; i < 2; i++)
        #pragma unroll
        for (int j = 0; j < 4; j++)
            #pragma unroll
            for (int r = 0; r < 4; r++) {
                int row = m0 + wm + i * 16 + q * 4 + r;
                int col = n0 + wn + j * 16 + lrow;
                if (row < M)
                    atomicAdd(&outF[(size_t)row * N + col], acc[i][j][r]);
            }
}

// -------- reduce1: h = relu(hacc + u + b1a) -> bf16; node-sum -> Shb bf16 --------
__global__ void reduce1(const float* __restrict__ hacc, const float* __restrict__ u,
                        const float* __restrict__ b1a,
                        u16* __restrict__ hb, u16* __restrict__ Shb) {
    __shared__ float sl[128];
    int bt = blockIdx.x, c0 = blockIdx.y * 128;
    int lc = threadIdx.x & 127, rp = threadIdx.x >> 7;
    int col = c0 + lc;
    float ub = u[bt * DH1 + col] + b1a[col];
    float s = 0.f;
    for (int n = rp; n < NOBJ; n += 2) {
        float v = hacc[(size_t)(bt * NOBJ + n) * DH1 + col] + ub;
        v = v > 0.f ? v : 0.f;
        hb[(size_t)(bt * NOBJ + n) * DH1 + col] = f2bf(v);
        s += v;
    }
    if (rp == 0) sl[lc] = s;
    __syncthreads();
    if (rp == 1) Shb[bt * DH1 + col] = f2bf(sl[lc] + s);
}

// -------- reduce2_qkv: g = mean_n relu(hacc2 + u2 + b1b); q,k,v = g @ W --------
__global__ void reduce2_qkv(const float* __restrict__ hacc2, const float* __restrict__ u2,
                            const float* __restrict__ b1b,
                            const float* __restrict__ Wq, const float* __restrict__ Wk,
                            const float* __restrict__ Wv,
                            float* __restrict__ g, float* __restrict__ q,
                            float* __restrict__ k, float* __restrict__ v) {
    __shared__ float gl[DH2];
    int bt = blockIdx.x, j = threadIdx.x;
    float ub = u2[bt * DH2 + j] + b1b[j];
    float a = 0.f;
    for (int n = 0; n < NOBJ; n++) {
        float vv = hacc2[(size_t)(bt * NOBJ + n) * DH2 + j] + ub;
        a += vv > 0.f ? vv : 0.f;
    }
    a *= (1.f / 30.f);
    gl[j] = a;
    g[bt * DH2 + j] = a;
    __syncthreads();
    float aq = 0.f, ak = 0.f, av = 0.f;
    for (int kk = 0; kk < DH2; kk++) {
        float x = gl[kk];
        aq += x * Wq[kk * DH2 + j];
        ak += x * Wk[kk * DH2 + j];
        av += x * Wv[kk * DH2 + j];
    }
    q[bt * DH2 + j] = aq;
    k[bt * DH2 + j] = ak;
    v[bt * DH2 + j] = av;
}

// -------- fused attention + Wo + LN1 + FFN + LN2 + classifier (block per row) --------
__device__ __forceinline__ float block_sum256(float v, volatile float* red) {
    #pragma unroll
    for (int o = 32; o > 0; o >>= 1) v += __shfl_down(v, o);
    int w = threadIdx.x >> 6;
    __syncthreads();
    if ((threadIdx.x & 63) == 0) red[w] = v;
    __syncthreads();
    return red[0] + red[1] + red[2] + red[3];
}

__global__ void attn_head(const float* __restrict__ qg, const float* __restrict__ kg,
                          const float* __restrict__ vg, const float* __restrict__ g,
                          const float* __restrict__ Wo,
                          const float* __restrict__ ln1g, const float* __restrict__ ln1b,
                          const float* __restrict__ Wf1, const float* __restrict__ bf1,
                          const float* __restrict__ Wf2, const float* __restrict__ bf2,
                          const float* __restrict__ ln2g, const float* __restrict__ ln2b,
                          const float* __restrict__ Wc, const float* __restrict__ bc,
                          float* __restrict__ out) {
    __shared__ float ql[DH2];
    __shared__ float scl[4][128];
    __shared__ float ctxl[DH2];
    __shared__ float yl[DH2];
    __shared__ float ffl[DFF];
    __shared__ float red[4];
    int row = blockIdx.x, tid = threadIdx.x;
    int base = (row >= 100) ? 100 : 0;
    ql[tid] = qg[row * DH2 + tid];
    __syncthreads();

    for (int p = tid; p < 512; p += 256) {
        int h = p >> 7, s = p & 127;
        if (s < 100) {
            const float* kr = kg + (size_t)(base + s) * DH2 + h * 64;
            float a = 0.f;
            #pragma unroll 8
            for (int d = 0; d < 64; d++) a += ql[h * 64 + d] * kr[d];
            scl[h][s] = a * 0.125f;
        }
    }
    __syncthreads();

    {
        int w = tid >> 6, lane = tid & 63;
        int s2 = 64 + lane;
        float a  = scl[w][lane];
        float b2 = (s2 < 100) ? scl[w][s2] : -1e30f;
        float m = fmaxf(a, b2);
        #pragma unroll
        for (int o = 32; o > 0; o >>= 1) m = fmaxf(m, __shfl_down(m, o));
        m = __shfl(m, 0);
        float e1 = __expf(a - m);
        float e2 = (s2 < 100) ? __expf(b2 - m) : 0.f;
        float sm = e1 + e2;
        #pragma unroll
        for (int o = 32; o > 0; o >>= 1) sm += __shfl_down(sm, o);
        sm = __shfl(sm, 0);
        float r = 1.f / sm;
        scl[w][lane] = e1 * r;
        if (s2 < 100) scl[w][s2] = e2 * r;
    }
    __syncthreads();

    {
        int h = tid >> 6;
        float o = 0.f;
        for (int s = 0; s < 100; s++)
            o += scl[h][s] * vg[(size_t)(base + s) * DH2 + tid];
        ctxl[tid] = o;
    }
    __syncthreads();

    float o = 0.f;
    for (int kk = 0; kk < DH2; kk++) o += ctxl[kk] * Wo[kk * DH2 + tid];
    float t = g[row * DH2 + tid] + o;
    float mu  = block_sum256(t, red) * (1.f / DH2);
    float ex2 = block_sum256(t * t, red) * (1.f / DH2);
    float y = (t - mu) * rsqrtf(ex2 - mu * mu + 1e-5f) * ln1g[tid] + ln1b[tid];
    yl[tid] = y;
    __syncthreads();
    for (int jj = tid; jj < DFF; jj += 256) {
        float a = bf1[jj];
        for (int kk = 0; kk < DH2; kk++) a += yl[kk] * Wf1[kk * DFF + jj];
        ffl[jj] = a > 0.f ? a : 0.f;
    }
    __syncthreads();
    float o2 = bf2[tid];
    for (int kk = 0; kk < DFF; kk++) o2 += ffl[kk] * Wf2[kk * DH2 + tid];
    float z0 = y + o2;
    float mu2  = block_sum256(z0, red) * (1.f / DH2);
    float ex22 = block_sum256(z0 * z0, red) * (1.f / DH2);
    float z = (z0 - mu2) * rsqrtf(ex22 - mu2 * mu2 + 1e-5f) * ln2g[tid] + ln2b[tid];
    float logit = block_sum256(z * Wc[tid], red) + bc[0];
    if (tid == 0) {
        out[row]      = 1.f / (1.f + __expf(-logit));
        out[BT + row] = 0.f;
    }
}

// ---------------- launch ----------------
extern "C" void kernel_launch(void* const* d_in, const int* in_sizes, int n_in,
                              void* d_out, int out_size, void* d_ws, size_t ws_size,
                              hipStream_t stream) {
    const float* feat  = (const float*)d_in[0];
    const float* depth = (const float*)d_in[1];
    const float* W1a = (const float*)d_in[2];
    const float* W2a = (const float*)d_in[3];
    const float* b1a = (const float*)d_in[4];
    const float* W1b = (const float*)d_in[5];
    const float* W2b = (const float*)d_in[6];
    const float* b1b = (const float*)d_in[7];
    const float* Wq  = (const float*)d_in[8];
    const float* Wk  = (const float*)d_in[9];
    const float* Wv  = (const float*)d_in[10];
    const float* Wo  = (const float*)d_in[11];
    const float* ln1g = (const float*)d_in[12];
    const float* ln1b = (const float*)d_in[13];
    const float* Wf1 = (const float*)d_in[14];
    const float* bf1 = (const float*)d_in[15];
    const float* Wf2 = (const float*)d_in[16];
    const float* bf2 = (const float*)d_in[17];
    const float* ln2g = (const float*)d_in[18];
    const float* ln2b = (const float*)d_in[19];
    const float* Wc  = (const float*)d_in[20];
    const float* bc  = (const float*)d_in[21];
    float* out = (float*)d_out;
    char* ws = (char*)d_ws;

    size_t off = 0;
    u16* Xb    = (u16*)(ws + off); off += (size_t)MPAD * KPAD * 2;   // 50.1 MB
    u16* Sb    = (u16*)(ws + off); off += (size_t)SPAD * KPAD * 2;
    u16* Wc1T  = (u16*)(ws + off); off += (size_t)DH1 * KPAD * 2;
    u16* W2aTs = (u16*)(ws + off); off += (size_t)DH1 * KPAD * 2;
    u16* Wc2T  = (u16*)(ws + off); off += (size_t)DH2 * DH1 * 2;
    u16* W2bTs = (u16*)(ws + off); off += (size_t)DH2 * DH1 * 2;
    u16* hb    = (u16*)(ws + off); off += (size_t)MPAD * DH1 * 2;
    u16* Shb   = (u16*)(ws + off); off += (size_t)SPAD * DH1 * 2;
    // contiguous zero-init region
    char* zBase = ws + off;
    float* hacc  = (float*)(ws + off); off += (size_t)6000 * DH1 * 4;  // 12.3 MB
    float* hacc2 = (float*)(ws + off); off += (size_t)6000 * DH2 * 4;  //  6.1 MB
    float* u     = (float*)(ws + off); off += (size_t)SPAD * DH1 * 4;
    float* u2    = (float*)(ws + off); off += (size_t)SPAD * DH2 * 4;
    size_t zBytes = (size_t)(ws + off - zBase);
    float* g   = (float*)(ws + off); off += (size_t)BT * DH2 * 4;
    float* q   = (float*)(ws + off); off += (size_t)BT * DH2 * 4;
    float* k   = (float*)(ws + off); off += (size_t)BT * DH2 * 4;
    float* v   = (float*)(ws + off); off += (size_t)BT * DH2 * 4;

    hipMemsetAsync(zBase, 0, zBytes, stream);
    prep_all<<<NBIG + NSMALL + NCONV, 256, 0, stream>>>(
        W1a, W2a, W1b, W2b, feat, depth, Wc1T, W2aTs, Wc2T, W2bTs, Xb, Sb);
    // hacc += Xb@Wc1T (564 blocks, z=3) ; u += Sb@W2aTs (48 blocks, z=6)
    gemmA<<<564 + 48, 256, 0, stream>>>(Xb, Wc1T, Sb, W2aTs, hacc, u);
    reduce1<<<dim3(BT, 4), 256, 0, stream>>>(hacc, u, b1a, hb, Shb);
    // hacc2 += hb@Wc2T (376 blocks, z=2) ; u2 += Shb@W2bTs (16 blocks, z=2)
    gemmB<<<376 + 16, 256, 0, stream>>>(hb, Wc2T, Shb, W2bTs, hacc2, u2);
    reduce2_qkv<<<BT, DH2, 0, stream>>>(hacc2, u2, b1b, Wq, Wk, Wv, g, q, k, v);
    attn_head<<<BT, DH2, 0, stream>>>(q, k, v, g, Wo, ln1g, ln1b, Wf1, bf1,
                                      Wf2, bf2, ln2g, ln2b, Wc, bc, out);
}

// Round 6
// 390.773 us; speedup vs baseline: 2.0162x; 1.0199x over previous
//
#include <hip/hip_runtime.h>
#include <hip/hip_bf16.h>
#include <stdint.h>

typedef unsigned short u16;
typedef __attribute__((ext_vector_type(8))) short short8;
typedef __attribute__((ext_vector_type(4))) float floatx4;
typedef __attribute__((ext_vector_type(4))) unsigned short ushort4_t;

#define BT 200      // B*T
#define NOBJ 30
#define KP2 4224    // 4097 padded to 3 z-slices x 22 iters x 64
#define DIN 4097
#define DH1 512
#define DH2 256
#define DFF 512
#define MPAD 6016
#define CHZ 176     // k-chunks (of 8) per z-slice
#define NBIGW (132*16)   // fold_big blocks (4224/32 x 512/32)
#define NSMALL 512
#define NCONV (BT*3)     // tiled sum_convert blocks
#define NZERO 128

__device__ __forceinline__ u16 f2bf(float f) {
    union { float f; uint32_t u; } c; c.f = f;
    uint32_t u = c.u;
    u += 0x7FFF + ((u >> 16) & 1);
    return (u16)(u >> 16);
}

// async global->LDS DMA, 16B/lane; LDS dest is wave-uniform base + lane*16
__device__ __forceinline__ void load16_lds(const u16* g, u16* l) {
    __builtin_amdgcn_global_load_lds(
        (const __attribute__((address_space(1))) void*)g,
        (__attribute__((address_space(3))) void*)l, 16, 0, 0);
}

// tiled offset: tiles of 128 rows x (3 z x 22 iters x 64 k), storage
// [tile147 = y*3+z][i][row][slot]*8 ; slot = kw ^ (row&7)  (pre-swizzled)
__device__ __forceinline__ size_t tile_off(int ytile, int row, int c8) {
    int z = c8 / CHZ, rem = c8 - z * CHZ;
    int i = rem >> 3, kw = rem & 7;
    int ks = kw ^ (row & 7);
    return ((((size_t)(ytile * 3 + z) * 22 + i) * 128 + row) * 64) + ks * 8;
}

// ======== prep_all: fold_big | fold_small | tiled sum_convert | zero ========
__global__ void prep_all(const float* __restrict__ W1a, const float* __restrict__ W2a,
                         const float* __restrict__ W1b, const float* __restrict__ W2b,
                         const float* __restrict__ feat, const float* __restrict__ depth,
                         u16* __restrict__ Wc1T, u16* __restrict__ W2aTs,
                         u16* __restrict__ Wc2T, u16* __restrict__ W2bTs,
                         u16* __restrict__ XbT, u16* __restrict__ SbT,
                         float* __restrict__ zeroBase, size_t zeroQuads) {
    __shared__ float t1[32][33];
    __shared__ float t2[32][33];
    int bid = blockIdx.x, tid = threadIdx.x;
    if (bid < NBIGW) {
        int kb = (bid % 132) * 32, jb = (bid / 132) * 32;
        int tx = tid & 31, ty = tid >> 5;   // 32 x 8
        #pragma unroll
        for (int r = 0; r < 32; r += 8) {
            int k = kb + ty + r, j = jb + tx;
            float a = 0.f, b = 0.f;
            if (k < DIN) { a = W1a[k * DH1 + j]; b = W2a[k * DH1 + j]; }
            float bs = b * (1.f / 29.f);
            t1[ty + r][tx] = a - bs;
            t2[ty + r][tx] = bs;
        }
        __syncthreads();
        #pragma unroll
        for (int r = 0; r < 32; r += 8) {
            int j = jb + ty + r, k = kb + tx;
            int x = j >> 7, row = j & 127;
            size_t off = tile_off(x, row, k >> 3) + (k & 7);
            Wc1T[off]  = f2bf(t1[tx][ty + r]);
            W2aTs[off] = f2bf(t2[tx][ty + r]);
        }
    } else if (bid < NBIGW + NSMALL) {
        int idx = (bid - NBIGW) * 256 + tid;   // 256*512 total
        int j = idx >> 9, k = idx & 511;
        float a = W1b[k * DH2 + j];
        float b = W2b[k * DH2 + j] * (1.f / 29.f);
        Wc2T[j * DH1 + k]  = f2bf(a - b);
        W2bTs[j * DH1 + k] = f2bf(b);
    } else if (bid < NBIGW + NSMALL + NCONV) {
        int cid = bid - NBIGW - NSMALL;
        int bt = cid / 3;
        int c8 = (cid % 3) * 256 + tid;
        if (c8 >= 528) return;
        int k8 = c8 * 8;
        float s[8] = {};
        for (int n = 0; n < NOBJ; n++) {
            int r = bt * NOBJ + n;
            float v[8];
            if (k8 + 7 < 4096) {
                float4 a = *(const float4*)(feat + (size_t)r * 4096 + k8);
                float4 b = *(const float4*)(feat + (size_t)r * 4096 + k8 + 4);
                v[0]=a.x; v[1]=a.y; v[2]=a.z; v[3]=a.w;
                v[4]=b.x; v[5]=b.y; v[6]=b.z; v[7]=b.w;
            } else {
                #pragma unroll
                for (int e = 0; e < 8; e++) v[e] = 0.f;
                if (k8 == 4096) v[0] = depth[r];
            }
            short8 o;
            #pragma unroll
            for (int e = 0; e < 8; e++) { s[e] += v[e]; o[e] = (short)f2bf(v[e]); }
            *(short8*)(XbT + tile_off(r >> 7, r & 127, c8)) = o;
        }
        short8 so;
        #pragma unroll
        for (int e = 0; e < 8; e++) so[e] = (short)f2bf(s[e]);
        *(short8*)(SbT + tile_off(bt >> 7, bt & 127, c8)) = so;
    } else {
        int zid = bid - NBIGW - NSMALL - NCONV;
        float4* p = (float4*)zeroBase;
        float4 zz = {0.f, 0.f, 0.f, 0.f};
        for (size_t idx = (size_t)zid * 256 + tid; idx < zeroQuads; idx += (size_t)NZERO * 256)
            p[idx] = zz;
    }
}

// ======== gemmA: 128x128 bf16 MFMA, contiguous tiled streams, split-K atomic ========
// seg0 (564): hacc += XbT @ Wc1T  (M=6000, N=512, z=3)
// seg1 ( 24): u    += SbT @ W2aTs (M=200,  N=512, z=3)
__global__ __launch_bounds__(256) void gemmA(
    const u16* __restrict__ XbT, const u16* __restrict__ WaT,
    const u16* __restrict__ SbT, const u16* __restrict__ WsT,
    float* __restrict__ hacc, float* __restrict__ uOut) {
    __shared__ __align__(16) u16 Al[8192];   // 16 KB
    __shared__ __align__(16) u16 Bl[8192];   // 16 KB
    int bid = blockIdx.x;
    const u16 *Abase, *Bbase;
    float* outF;
    int m0, n0, M;
    if (bid < 564) {
        int x = bid & 3, y = (bid >> 2) % 47, z = bid / 188;
        Abase = XbT + (size_t)((y * 3 + z) * 22) * 8192;
        Bbase = WaT + (size_t)((x * 3 + z) * 22) * 8192;
        outF = hacc; M = 6000; m0 = y * 128; n0 = x * 128;
    } else {
        int rem = bid - 564;
        int x = rem & 3, y = (rem >> 2) & 1, z = rem >> 3;
        Abase = SbT + (size_t)((y * 3 + z) * 22) * 8192;
        Bbase = WsT + (size_t)((x * 3 + z) * 22) * 8192;
        outF = uOut; M = BT; m0 = y * 128; n0 = x * 128;
    }
    int tid = threadIdx.x, lane = tid & 63, w = tid >> 6;
    floatx4 acc[4][4] = {};
    int lrow = lane & 15, q = lane >> 4;
    int wm = (w & 1) * 64, wn = (w >> 1) * 64;
    int swz = lrow & 7;

    for (int i = 0; i < 22; i++) {
        const u16* as = Abase + (size_t)i * 8192;
        const u16* bs = Bbase + (size_t)i * 8192;
        #pragma unroll
        for (int it = 0; it < 4; it++) {
            load16_lds(as + (it * 256 + tid) * 8, Al + it * 2048 + w * 512);
            load16_lds(bs + (it * 256 + tid) * 8, Bl + it * 2048 + w * 512);
        }
        __syncthreads();
        #pragma unroll
        for (int h = 0; h < 2; h++) {
            int ci = h * 4 + q;
            int so = (ci ^ swz) * 8;
            short8 af[4], bfv[4];
            #pragma unroll
            for (int ii = 0; ii < 4; ii++)
                af[ii] = *(short8*)(Al + (wm + ii * 16 + lrow) * 64 + so);
            #pragma unroll
            for (int j = 0; j < 4; j++)
                bfv[j] = *(short8*)(Bl + (wn + j * 16 + lrow) * 64 + so);
            #pragma unroll
            for (int ii = 0; ii < 4; ii++)
                #pragma unroll
                for (int j = 0; j < 4; j++)
                    acc[ii][j] = __builtin_amdgcn_mfma_f32_16x16x32_bf16(af[ii], bfv[j], acc[ii][j], 0, 0, 0);
        }
        __syncthreads();
    }

    #pragma unroll
    for (int ii = 0; ii < 4; ii++)
        #pragma unroll
        for (int j = 0; j < 4; j++)
            #pragma unroll
            for (int r = 0; r < 4; r++) {
                int row = m0 + wm + ii * 16 + q * 4 + r;
                int col = n0 + wn + j * 16 + lrow;
                if (row < M)
                    atomicAdd(&outF[(size_t)row * DH1 + col], acc[ii][j][r]);
            }
}

// ======== gemmB: 64x128 bf16 MFMA, BK=64, on-the-fly swizzle, split-K atomic ========
// seg0 (376): hacc2 += hb @ Wc2T   (M=6000, z=2 x 4 iters)
// seg1 ( 16): u2    += Shb @ W2bTs (M=200,  z=2 x 4 iters)
__global__ __launch_bounds__(256) void gemmB(
    const u16* __restrict__ hb, const u16* __restrict__ Wc2T,
    const u16* __restrict__ Shb, const u16* __restrict__ W2bTs,
    float* __restrict__ hacc2, float* __restrict__ u2Out) {
    __shared__ __align__(16) u16 Al[64 * 64];    // 8 KB
    __shared__ __align__(16) u16 Bl[128 * 64];   // 16 KB
    int bid = blockIdx.x;
    const u16 *A, *B;
    float* outF;
    int m0, n0, kbeg, M;
    if (bid < 376) {
        int x = bid & 1, y = (bid >> 1) % 94, z = bid / 188;
        A = hb; B = Wc2T; outF = hacc2; M = 6000;
        m0 = y * 64; n0 = x * 128; kbeg = z * 256;
    } else {
        int rem = bid - 376;
        int x = rem & 1, y = (rem >> 1) & 3, z = rem >> 3;
        A = Shb; B = W2bTs; outF = u2Out; M = BT;
        m0 = y * 64; n0 = x * 128; kbeg = z * 256;
    }
    int kend = kbeg + 256;
    const int N = DH2, K = DH1;
    int tid = threadIdx.x;
    int lane = tid & 63, w = tid >> 6;
    int srow = tid >> 3, kslot = tid & 7;
    floatx4 acc[2][4] = {};
    int lrow = lane & 15, q = lane >> 4;
    int wm = (w & 1) * 32, wn = (w >> 1) * 64;
    int swz = lrow & 7;

    for (int kb = kbeg; kb < kend; kb += 64) {
        #pragma unroll
        for (int it = 0; it < 2; it++) {
            int row = it * 32 + srow;
            int kph = kslot ^ (row & 7);
            load16_lds(A + (size_t)(m0 + row) * K + kb + kph * 8,
                       Al + it * 2048 + w * 512);
        }
        #pragma unroll
        for (int it = 0; it < 4; it++) {
            int row = it * 32 + srow;
            int kph = kslot ^ (row & 7);
            load16_lds(B + (size_t)(n0 + row) * K + kb + kph * 8,
                       Bl + it * 2048 + w * 512);
        }
        __syncthreads();
        #pragma unroll
        for (int h = 0; h < 2; h++) {
            int ci = h * 4 + q;
            int so = (ci ^ swz) * 8;
            short8 af[2], bfv[4];
            #pragma unroll
            for (int i = 0; i < 2; i++)
                af[i] = *(short8*)(Al + (wm + i * 16 + lrow) * 64 + so);
            #pragma unroll
            for (int j = 0; j < 4; j++)
                bfv[j] = *(short8*)(Bl + (wn + j * 16 + lrow) * 64 + so);
            #pragma unroll
            for (int i = 0; i < 2; i++)
                #pragma unroll
                for (int j = 0; j < 4; j++)
                    acc[i][j] = __builtin_amdgcn_mfma_f32_16x16x32_bf16(af[i], bfv[j], acc[i][j], 0, 0, 0);
        }
        __syncthreads();
    }

    #pragma unroll
    for (int i = 0; i < 2; i++)
        #pragma unroll
        for (int j = 0; j < 4; j++)
            #pragma unroll
            for (int r = 0; r < 4; r++) {
                int row = m0 + wm + i * 16 + q * 4 + r;
                int col = n0 + wn + j * 16 + lrow;
                if (row < M)
                    atomicAdd(&outF[(size_t)row * N + col], acc[i][j][r]);
            }
}

// -------- reduce1: h = relu(hacc + u + b1a) -> bf16 hb; node-sum -> Shb --------
__global__ void reduce1(const float* __restrict__ hacc, const float* __restrict__ u,
                        const float* __restrict__ b1a,
                        u16* __restrict__ hb, u16* __restrict__ Shb) {
    __shared__ float sl[128];
    int bt = blockIdx.x, c0 = blockIdx.y * 128;
    int lc = threadIdx.x & 127, rp = threadIdx.x >> 7;
    int col = c0 + lc;
    float ub = u[bt * DH1 + col] + b1a[col];
    float s = 0.f;
    for (int n = rp; n < NOBJ; n += 2) {
        float v = hacc[(size_t)(bt * NOBJ + n) * DH1 + col] + ub;
        v = v > 0.f ? v : 0.f;
        hb[(size_t)(bt * NOBJ + n) * DH1 + col] = f2bf(v);
        s += v;
    }
    if (rp == 0) sl[lc] = s;
    __syncthreads();
    if (rp == 1) Shb[bt * DH1 + col] = f2bf(sl[lc] + s);
}

// -------- reduce2_qkv: g = mean_n relu(hacc2 + u2 + b1b); q,k,v = g @ W --------
__global__ void reduce2_qkv(const float* __restrict__ hacc2, const float* __restrict__ u2,
                            const float* __restrict__ b1b,
                            const float* __restrict__ Wq, const float* __restrict__ Wk,
                            const float* __restrict__ Wv,
                            float* __restrict__ g, float* __restrict__ q,
                            float* __restrict__ k, float* __restrict__ v) {
    __shared__ float gl[DH2];
    int bt = blockIdx.x, j = threadIdx.x;
    float ub = u2[bt * DH2 + j] + b1b[j];
    float a = 0.f;
    for (int n = 0; n < NOBJ; n++) {
        float vv = hacc2[(size_t)(bt * NOBJ + n) * DH2 + j] + ub;
        a += vv > 0.f ? vv : 0.f;
    }
    a *= (1.f / 30.f);
    gl[j] = a;
    g[bt * DH2 + j] = a;
    __syncthreads();
    float aq = 0.f, ak = 0.f, av = 0.f;
    for (int kk = 0; kk < DH2; kk++) {
        float x = gl[kk];
        aq += x * Wq[kk * DH2 + j];
        ak += x * Wk[kk * DH2 + j];
        av += x * Wv[kk * DH2 + j];
    }
    q[bt * DH2 + j] = aq;
    k[bt * DH2 + j] = ak;
    v[bt * DH2 + j] = av;
}

// -------- fused attention + Wo + LN1 + FFN + LN2 + classifier --------
__device__ __forceinline__ float block_sum256(float v, volatile float* red) {
    #pragma unroll
    for (int o = 32; o > 0; o >>= 1) v += __shfl_down(v, o);
    int w = threadIdx.x >> 6;
    __syncthreads();
    if ((threadIdx.x & 63) == 0) red[w] = v;
    __syncthreads();
    return red[0] + red[1] + red[2] + red[3];
}

__global__ void attn_head(const float* __restrict__ qg, const float* __restrict__ kg,
                          const float* __restrict__ vg, const float* __restrict__ g,
                          const float* __restrict__ Wo,
                          const float* __restrict__ ln1g, const float* __restrict__ ln1b,
                          const float* __restrict__ Wf1, const float* __restrict__ bf1,
                          const float* __restrict__ Wf2, const float* __restrict__ bf2,
                          const float* __restrict__ ln2g, const float* __restrict__ ln2b,
                          const float* __restrict__ Wc, const float* __restrict__ bc,
                          float* __restrict__ out) {
    __shared__ float ql[DH2];
    __shared__ float scl[4][128];
    __shared__ float ctxl[DH2];
    __shared__ float yl[DH2];
    __shared__ float ffl[DFF];
    __shared__ float red[4];
    int row = blockIdx.x, tid = threadIdx.x;
    int base = (row >= 100) ? 100 : 0;
    ql[tid] = qg[row * DH2 + tid];
    __syncthreads();

    for (int p = tid; p < 512; p += 256) {
        int h = p >> 7, s = p & 127;
        if (s < 100) {
            const float* kr = kg + (size_t)(base + s) * DH2 + h * 64;
            float a = 0.f;
            #pragma unroll 8
            for (int d = 0; d < 64; d++) a += ql[h * 64 + d] * kr[d];
            scl[h][s] = a * 0.125f;
        }
    }
    __syncthreads();

    {
        int w = tid >> 6, lane = tid & 63;
        int s2 = 64 + lane;
        float a  = scl[w][lane];
        float b2 = (s2 < 100) ? scl[w][s2] : -1e30f;
        float m = fmaxf(a, b2);
        #pragma unroll
        for (int o = 32; o > 0; o >>= 1) m = fmaxf(m, __shfl_down(m, o));
        m = __shfl(m, 0);
        float e1 = __expf(a - m);
        float e2 = (s2 < 100) ? __expf(b2 - m) : 0.f;
        float sm = e1 + e2;
        #pragma unroll
        for (int o = 32; o > 0; o >>= 1) sm += __shfl_down(sm, o);
        sm = __shfl(sm, 0);
        float r = 1.f / sm;
        scl[w][lane] = e1 * r;
        if (s2 < 100) scl[w][s2] = e2 * r;
    }
    __syncthreads();

    {
        int h = tid >> 6;
        float o = 0.f;
        for (int s = 0; s < 100; s++)
            o += scl[h][s] * vg[(size_t)(base + s) * DH2 + tid];
        ctxl[tid] = o;
    }
    __syncthreads();

    float o = 0.f;
    for (int kk = 0; kk < DH2; kk++) o += ctxl[kk] * Wo[kk * DH2 + tid];
    float t = g[row * DH2 + tid] + o;
    float mu  = block_sum256(t, red) * (1.f / DH2);
    float ex2 = block_sum256(t * t, red) * (1.f / DH2);
    float y = (t - mu) * rsqrtf(ex2 - mu * mu + 1e-5f) * ln1g[tid] + ln1b[tid];
    yl[tid] = y;
    __syncthreads();
    for (int jj = tid; jj < DFF; jj += 256) {
        float a = bf1[jj];
        for (int kk = 0; kk < DH2; kk++) a += yl[kk] * Wf1[kk * DFF + jj];
        ffl[jj] = a > 0.f ? a : 0.f;
    }
    __syncthreads();
    float o2 = bf2[tid];
    for (int kk = 0; kk < DFF; kk++) o2 += ffl[kk] * Wf2[kk * DH2 + tid];
    float z0 = y + o2;
    float mu2  = block_sum256(z0, red) * (1.f / DH2);
    float ex22 = block_sum256(z0 * z0, red) * (1.f / DH2);
    float z = (z0 - mu2) * rsqrtf(ex22 - mu2 * mu2 + 1e-5f) * ln2g[tid] + ln2b[tid];
    float logit = block_sum256(z * Wc[tid], red) + bc[0];
    if (tid == 0) {
        out[row]      = 1.f / (1.f + __expf(-logit));
        out[BT + row] = 0.f;
    }
}

// ---------------- launch ----------------
extern "C" void kernel_launch(void* const* d_in, const int* in_sizes, int n_in,
                              void* d_out, int out_size, void* d_ws, size_t ws_size,
                              hipStream_t stream) {
    const float* feat  = (const float*)d_in[0];
    const float* depth = (const float*)d_in[1];
    const float* W1a = (const float*)d_in[2];
    const float* W2a = (const float*)d_in[3];
    const float* b1a = (const float*)d_in[4];
    const float* W1b = (const float*)d_in[5];
    const float* W2b = (const float*)d_in[6];
    const float* b1b = (const float*)d_in[7];
    const float* Wq  = (const float*)d_in[8];
    const float* Wk  = (const float*)d_in[9];
    const float* Wv  = (const float*)d_in[10];
    const float* Wo  = (const float*)d_in[11];
    const float* ln1g = (const float*)d_in[12];
    const float* ln1b = (const float*)d_in[13];
    const float* Wf1 = (const float*)d_in[14];
    const float* bf1 = (const float*)d_in[15];
    const float* Wf2 = (const float*)d_in[16];
    const float* bf2 = (const float*)d_in[17];
    const float* ln2g = (const float*)d_in[18];
    const float* ln2b = (const float*)d_in[19];
    const float* Wc  = (const float*)d_in[20];
    const float* bc  = (const float*)d_in[21];
    float* out = (float*)d_out;
    char* ws = (char*)d_ws;

    size_t off = 0;
    u16* XbT   = (u16*)(ws + off); off += (size_t)MPAD * KP2 * 2;    // 50.8 MB
    u16* SbT   = (u16*)(ws + off); off += (size_t)256 * KP2 * 2;     //  2.2 MB
    u16* Wc1T  = (u16*)(ws + off); off += (size_t)DH1 * KP2 * 2;     //  4.3 MB
    u16* W2aTs = (u16*)(ws + off); off += (size_t)DH1 * KP2 * 2;
    u16* Wc2T  = (u16*)(ws + off); off += (size_t)DH2 * DH1 * 2;
    u16* W2bTs = (u16*)(ws + off); off += (size_t)DH2 * DH1 * 2;
    u16* Shb   = (u16*)(ws + off); off += (size_t)256 * DH1 * 2;
    // contiguous zero region (cleared by prep_all)
    char* zBase = ws + off;
    float* hacc  = (float*)(ws + off); off += (size_t)6000 * DH1 * 4;  // 12.3 MB
    float* hacc2 = (float*)(ws + off); off += (size_t)6000 * DH2 * 4;  //  6.1 MB
    float* u     = (float*)(ws + off); off += (size_t)BT * DH1 * 4;
    float* u2    = (float*)(ws + off); off += (size_t)BT * DH2 * 4;
    size_t zeroQuads = (size_t)(ws + off - zBase) / 16;
    // aliases: hb reuses XbT (dead after gemmA); g/q/k/v reuse SbT (dead after gemmA)
    u16* hb = XbT;
    float* g = (float*)SbT;
    float* q = g + BT * DH2;
    float* k = q + BT * DH2;
    float* v = k + BT * DH2;

    prep_all<<<NBIGW + NSMALL + NCONV + NZERO, 256, 0, stream>>>(
        W1a, W2a, W1b, W2b, feat, depth,
        Wc1T, W2aTs, Wc2T, W2bTs, XbT, SbT, (float*)zBase, zeroQuads);
    // hacc += XbT@Wc1T (564 blocks, z=3) ; u += SbT@W2aTs (24 blocks, z=3)
    gemmA<<<564 + 24, 256, 0, stream>>>(XbT, Wc1T, SbT, W2aTs, hacc, u);
    reduce1<<<dim3(BT, 4), 256, 0, stream>>>(hacc, u, b1a, hb, Shb);
    // hacc2 += hb@Wc2T (376 blocks, z=2) ; u2 += Shb@W2bTs (16 blocks, z=2)
    gemmB<<<376 + 16, 256, 0, stream>>>(hb, Wc2T, Shb, W2bTs, hacc2, u2);
    reduce2_qkv<<<BT, DH2, 0, stream>>>(hacc2, u2, b1b, Wq, Wk, Wv, g, q, k, v);
    attn_head<<<BT, DH2, 0, stream>>>(q, k, v, g, Wo, ln1g, ln1b, Wf1, bf1,
                                      Wf2, bf2, ln2g, ln2b, Wc, bc, out);
}